// Round 1
// baseline (896.116 us; speedup 1.0000x reference)
//
#include <hip/hip_runtime.h>

// R1: correct fp32 baseline.
//   K-projection trick: reference K = (x@Wk+bk).reshape(B,H,S,D) is a pure
//   reinterpret of the [B,S,E] buffer -> K head h of batch b is contiguous
//   [S=2048][D=64] at Klin + b*S*E + h*S*D.
//   ws layout (f32): Qlin | Klin | Vlin | AO, each B*S*E = 4M floats (64MB).

#define S_LEN 2048
#define EMB   1024
#define HEADS 16
#define HDIM  64
#define WIN   256

// ---------------- GEMM: Y = X @ W + bias  (X[M,K], W[K,N]) -----------------
// 128x128 tile, BK=16, 256 threads, 8x8 micro-tile. blockIdx.z selects weight.
__global__ __launch_bounds__(256)
void gemm3_kernel(const float* __restrict__ X,
                  const float* __restrict__ W0, const float* __restrict__ W1,
                  const float* __restrict__ W2,
                  const float* __restrict__ b0, const float* __restrict__ b1,
                  const float* __restrict__ b2,
                  float* __restrict__ Y0, float* __restrict__ Y1,
                  float* __restrict__ Y2,
                  int M, int N, int K)
{
    const int z = blockIdx.z;
    const float* W    = (z == 0) ? W0 : (z == 1) ? W1 : W2;
    const float* bias = (z == 0) ? b0 : (z == 1) ? b1 : b2;
    float*       Y    = (z == 0) ? Y0 : (z == 1) ? Y1 : Y2;

    __shared__ float As[16][128];   // [k][m] (A stored transposed)
    __shared__ float Bs[16][128];   // [k][n]

    const int tid = threadIdx.x;
    const int ty  = tid >> 4;       // 0..15 -> rows ty*8..+7
    const int tx  = tid & 15;       // 0..15 -> cols tx*8..+7
    const int bm  = blockIdx.y * 128;
    const int bn  = blockIdx.x * 128;

    float acc[8][8];
#pragma unroll
    for (int i = 0; i < 8; ++i)
#pragma unroll
        for (int j = 0; j < 8; ++j) acc[i][j] = 0.0f;

    for (int k0 = 0; k0 < K; k0 += 16) {
        // stage A tile 128x16 (transposed into As[k][m])
#pragma unroll
        for (int q = 0; q < 2; ++q) {
            int idx = tid + q * 256;          // 0..511
            int r   = idx >> 2;               // 0..127
            int c   = (idx & 3) << 2;         // 0,4,8,12
            float4 v = *reinterpret_cast<const float4*>(
                X + (size_t)(bm + r) * K + k0 + c);
            As[c + 0][r] = v.x;
            As[c + 1][r] = v.y;
            As[c + 2][r] = v.z;
            As[c + 3][r] = v.w;
        }
        // stage B tile 16x128
#pragma unroll
        for (int q = 0; q < 2; ++q) {
            int idx = tid + q * 256;          // 0..511
            int r   = idx >> 5;               // 0..15
            int c   = (idx & 31) << 2;        // 0..124
            float4 v = *reinterpret_cast<const float4*>(
                W + (size_t)(k0 + r) * N + bn + c);
            *reinterpret_cast<float4*>(&Bs[r][c]) = v;
        }
        __syncthreads();

#pragma unroll
        for (int kk = 0; kk < 16; ++kk) {
            float a[8], bb[8];
            *reinterpret_cast<float4*>(&a[0]) =
                *reinterpret_cast<const float4*>(&As[kk][ty * 8]);
            *reinterpret_cast<float4*>(&a[4]) =
                *reinterpret_cast<const float4*>(&As[kk][ty * 8 + 4]);
            *reinterpret_cast<float4*>(&bb[0]) =
                *reinterpret_cast<const float4*>(&Bs[kk][tx * 8]);
            *reinterpret_cast<float4*>(&bb[4]) =
                *reinterpret_cast<const float4*>(&Bs[kk][tx * 8 + 4]);
#pragma unroll
            for (int i = 0; i < 8; ++i)
#pragma unroll
                for (int j = 0; j < 8; ++j)
                    acc[i][j] = fmaf(a[i], bb[j], acc[i][j]);
        }
        __syncthreads();
    }

#pragma unroll
    for (int i = 0; i < 8; ++i) {
        size_t row = (size_t)(bm + ty * 8 + i) * N + bn + tx * 8;
#pragma unroll
        for (int j = 0; j < 8; j += 4) {
            float4 o;
            o.x = acc[i][j + 0] + bias[bn + tx * 8 + j + 0];
            o.y = acc[i][j + 1] + bias[bn + tx * 8 + j + 1];
            o.z = acc[i][j + 2] + bias[bn + tx * 8 + j + 2];
            o.w = acc[i][j + 3] + bias[bn + tx * 8 + j + 3];
            *reinterpret_cast<float4*>(Y + row + j) = o;
        }
    }
}

// --------------- sliding-window attention, fp32, flash-style ---------------
// One block per (q-block of 64 rows, head, batch). 256 threads, 4x4/thread.
__global__ __launch_bounds__(256)
void attn_kernel(const float* __restrict__ Qlin, const float* __restrict__ Klin,
                 const float* __restrict__ Vlin, float* __restrict__ AO)
{
    __shared__ float Qs[64][68];   // [d][r]
    __shared__ float Ks[64][68];   // [d][j]
    __shared__ float Vs[64][68];   // [j][d]
    __shared__ float Ps[64][68];   // [j][r] (P transposed)

    const int qb  = blockIdx.x;          // 0..31
    const int h   = blockIdx.y;          // 0..15
    const int b   = blockIdx.z;          // 0..B-1
    const int i0  = qb * 64;
    const int tid = threadIdx.x;
    const int ty  = tid >> 4;            // rows ty*4..+3
    const int tx  = tid & 15;            // cols tx*4..+3

    // contiguous K head (the reshape(B,H,S,D) "bug")
    const float* Kh = Klin + (size_t)b * S_LEN * EMB + (size_t)h * S_LEN * HDIM;

    // stage Q tile transposed: Qs[d][r]
#pragma unroll
    for (int q = 0; q < 4; ++q) {
        int idx = tid + q * 256;          // 0..1023
        int r   = idx >> 4;               // 0..63
        int c   = (idx & 15) << 2;        // 0..60
        float4 v = *reinterpret_cast<const float4*>(
            Qlin + ((size_t)b * S_LEN + i0 + r) * EMB + h * HDIM + c);
        Qs[c + 0][r] = v.x;
        Qs[c + 1][r] = v.y;
        Qs[c + 2][r] = v.z;
        Qs[c + 3][r] = v.w;
    }

    float m[4], l[4], o[4][4];
#pragma unroll
    for (int i = 0; i < 4; ++i) {
        m[i] = -1e30f;
        l[i] = 0.0f;
#pragma unroll
        for (int j = 0; j < 4; ++j) o[i][j] = 0.0f;
    }

    int tlo = qb - 4; if (tlo < 0) tlo = 0;
    int thi = qb + 4; if (thi > (S_LEN / 64 - 1)) thi = S_LEN / 64 - 1;

    for (int t = tlo; t <= thi; ++t) {
        // stage K (transposed) and V tiles
#pragma unroll
        for (int q = 0; q < 4; ++q) {
            int idx = tid + q * 256;
            int j   = idx >> 4;           // 0..63
            int c   = (idx & 15) << 2;    // 0..60
            int jg  = t * 64 + j;         // always in [0,S)
            float4 kv = *reinterpret_cast<const float4*>(
                Kh + (size_t)jg * HDIM + c);
            Ks[c + 0][j] = kv.x;
            Ks[c + 1][j] = kv.y;
            Ks[c + 2][j] = kv.z;
            Ks[c + 3][j] = kv.w;
            float4 vv = *reinterpret_cast<const float4*>(
                Vlin + ((size_t)b * S_LEN + jg) * EMB + h * HDIM + c);
            *reinterpret_cast<float4*>(&Vs[j][c]) = vv;
        }
        __syncthreads();

        // QK^T 64x64 tile, 4x4 per thread
        float s[4][4];
#pragma unroll
        for (int i = 0; i < 4; ++i)
#pragma unroll
            for (int j = 0; j < 4; ++j) s[i][j] = 0.0f;

#pragma unroll
        for (int d = 0; d < 64; ++d) {
            float qr[4], kr[4];
            *reinterpret_cast<float4*>(qr) =
                *reinterpret_cast<const float4*>(&Qs[d][ty * 4]);
            *reinterpret_cast<float4*>(kr) =
                *reinterpret_cast<const float4*>(&Ks[d][tx * 4]);
#pragma unroll
            for (int i = 0; i < 4; ++i)
#pragma unroll
                for (int j = 0; j < 4; ++j)
                    s[i][j] = fmaf(qr[i], kr[j], s[i][j]);
        }

        // scale + window mask + per-row tile max
        float tmax[4];
#pragma unroll
        for (int i = 0; i < 4; ++i) tmax[i] = -1e30f;
#pragma unroll
        for (int i = 0; i < 4; ++i) {
            int ig = i0 + ty * 4 + i;
#pragma unroll
            for (int j = 0; j < 4; ++j) {
                int jg = t * 64 + tx * 4 + j;
                bool ok = (jg >= ig - WIN) && (jg < ig + WIN);
                float val = ok ? s[i][j] * 0.125f : -1e30f;
                s[i][j] = val;
                tmax[i] = fmaxf(tmax[i], val);
            }
        }
#pragma unroll
        for (int off = 1; off < 16; off <<= 1)
#pragma unroll
            for (int i = 0; i < 4; ++i)
                tmax[i] = fmaxf(tmax[i], __shfl_xor(tmax[i], off));

        // online softmax update
        float sc[4], psum[4];
#pragma unroll
        for (int i = 0; i < 4; ++i) {
            float mn = fmaxf(m[i], tmax[i]);
            sc[i] = __expf(m[i] - mn);
            m[i] = mn;
            float ps = 0.0f;
#pragma unroll
            for (int j = 0; j < 4; ++j) {
                float p = __expf(s[i][j] - mn);
                s[i][j] = p;
                ps += p;
            }
            psum[i] = ps;
        }
#pragma unroll
        for (int off = 1; off < 16; off <<= 1)
#pragma unroll
            for (int i = 0; i < 4; ++i)
                psum[i] += __shfl_xor(psum[i], off);
#pragma unroll
        for (int i = 0; i < 4; ++i) {
            l[i] = l[i] * sc[i] + psum[i];
#pragma unroll
            for (int j = 0; j < 4; ++j) o[i][j] *= sc[i];
        }

        // write P transposed: Ps[j][r]
#pragma unroll
        for (int i = 0; i < 4; ++i)
#pragma unroll
            for (int j = 0; j < 4; ++j)
                Ps[tx * 4 + j][ty * 4 + i] = s[i][j];
        __syncthreads();

        // PV: o[r][d] += P[r][j] * V[j][d]
#pragma unroll
        for (int j = 0; j < 64; ++j) {
            float pr[4], vr[4];
            *reinterpret_cast<float4*>(pr) =
                *reinterpret_cast<const float4*>(&Ps[j][ty * 4]);
            *reinterpret_cast<float4*>(vr) =
                *reinterpret_cast<const float4*>(&Vs[j][tx * 4]);
#pragma unroll
            for (int i = 0; i < 4; ++i)
#pragma unroll
                for (int d = 0; d < 4; ++d)
                    o[i][d] = fmaf(pr[i], vr[d], o[i][d]);
        }
        __syncthreads();
    }

    // normalize + write AO[b, i0+r, h*64+d]
#pragma unroll
    for (int i = 0; i < 4; ++i) {
        float inv = 1.0f / l[i];
        float4 ov;
        ov.x = o[i][0] * inv;
        ov.y = o[i][1] * inv;
        ov.z = o[i][2] * inv;
        ov.w = o[i][3] * inv;
        *reinterpret_cast<float4*>(
            AO + ((size_t)b * S_LEN + i0 + ty * 4 + i) * EMB + h * HDIM + tx * 4) = ov;
    }
}

extern "C" void kernel_launch(void* const* d_in, const int* in_sizes, int n_in,
                              void* d_out, int out_size, void* d_ws, size_t ws_size,
                              hipStream_t stream)
{
    (void)n_in; (void)out_size; (void)ws_size;
    const float* x  = (const float*)d_in[0];
    const float* Wq = (const float*)d_in[1];
    const float* bq = (const float*)d_in[2];
    const float* Wk = (const float*)d_in[3];
    const float* bk = (const float*)d_in[4];
    const float* Wv = (const float*)d_in[5];
    const float* bv = (const float*)d_in[6];
    const float* Wo = (const float*)d_in[7];
    const float* bo = (const float*)d_in[8];
    float* out = (float*)d_out;

    const int B = in_sizes[0] / (S_LEN * EMB);   // = 2
    const int M = B * S_LEN;                     // 4096

    float* Qlin = (float*)d_ws;
    float* Klin = Qlin + (size_t)M * EMB;
    float* Vlin = Klin + (size_t)M * EMB;
    float* AO   = Vlin + (size_t)M * EMB;

    // 1) fused QKV projections
    dim3 g1(EMB / 128, M / 128, 3);
    gemm3_kernel<<<g1, 256, 0, stream>>>(x, Wq, Wk, Wv, bq, bk, bv,
                                         Qlin, Klin, Vlin, M, EMB, EMB);

    // 2) sliding-window attention -> AO in [B,S,E] layout
    dim3 g2(S_LEN / 64, HEADS, B);
    attn_kernel<<<g2, 256, 0, stream>>>(Qlin, Klin, Vlin, AO);

    // 3) output projection
    dim3 g3(EMB / 128, M / 128, 1);
    gemm3_kernel<<<g3, 256, 0, stream>>>(AO, Wo, Wo, Wo, bo, bo, bo,
                                         out, out, out, M, EMB, EMB);
}

// Round 2
// 306.118 us; speedup vs baseline: 2.9274x; 2.9274x over previous
//
#include <hip/hip_runtime.h>

#define S_LEN 2048
#define EMB   1024
#define HEADS 16
#define HDIM  64
#define WIN   256

typedef unsigned short u16;
typedef unsigned int   u32;
typedef float  f32x4  __attribute__((ext_vector_type(4)));
typedef __bf16 bf16x8 __attribute__((ext_vector_type(8)));
typedef unsigned short u16x4 __attribute__((ext_vector_type(4)));

__device__ __forceinline__ u16 f2bf(float v) {            // RNE f32->bf16
    u32 x = __builtin_bit_cast(u32, v);
    return (u16)((x + 0x7fffu + ((x >> 16) & 1u)) >> 16);
}
__device__ __forceinline__ float bf2f(u16 v) {
    u32 x = ((u32)v) << 16;
    return __builtin_bit_cast(float, x);
}
__device__ __forceinline__ void unpack2(u32 w, float& lo, float& hi) {
    lo = __builtin_bit_cast(float, w << 16);
    hi = __builtin_bit_cast(float, w & 0xffff0000u);
}

// ---------------- x (f32) -> bf16 ----------------
__global__ void convert_bf16_kernel(const float* __restrict__ in,
                                    u16* __restrict__ out, int n4)
{
    int i = blockIdx.x * blockDim.x + threadIdx.x;
    if (i >= n4) return;
    float4 v = reinterpret_cast<const float4*>(in)[i];
    u16x4 o;
    o[0] = f2bf(v.x); o[1] = f2bf(v.y); o[2] = f2bf(v.z); o[3] = f2bf(v.w);
    reinterpret_cast<u16x4*>(out)[i] = o;
}

// ------------- W[k][n] f32 -> Wt[n][k] bf16 (+lo for z==3) -------------
__global__ __launch_bounds__(256)
void transpose_w_kernel(const float* __restrict__ W0, const float* __restrict__ W1,
                        const float* __restrict__ W2, const float* __restrict__ W3,
                        u16* __restrict__ T0, u16* __restrict__ T1,
                        u16* __restrict__ T2, u16* __restrict__ T3,
                        u16* __restrict__ T3lo)
{
    const int z = blockIdx.z;
    const float* W = (z == 0) ? W0 : (z == 1) ? W1 : (z == 2) ? W2 : W3;
    u16* T = (z == 0) ? T0 : (z == 1) ? T1 : (z == 2) ? T2 : T3;

    __shared__ float Ts[64][68];
    const int tid = threadIdx.x;
    const int k0 = blockIdx.x * 64, n0 = blockIdx.y * 64;

    int r = tid >> 2, c0 = (tid & 3) * 16;
#pragma unroll
    for (int q = 0; q < 4; ++q) {
        float4 v = *reinterpret_cast<const float4*>(W + (size_t)(k0 + r) * EMB + n0 + c0 + 4 * q);
        *reinterpret_cast<float4*>(&Ts[r][c0 + 4 * q]) = v;
    }
    __syncthreads();

    int n = tid >> 2, kk0 = (tid & 3) * 16;
    u16 hb[16], lb[16];
#pragma unroll
    for (int e = 0; e < 16; ++e) {
        float f = Ts[kk0 + e][n];
        hb[e] = f2bf(f);
        lb[e] = f2bf(f - bf2f(hb[e]));
    }
    size_t base = (size_t)(n0 + n) * EMB + k0 + kk0;
#pragma unroll
    for (int q = 0; q < 2; ++q) {
        u32 w[4];
#pragma unroll
        for (int e = 0; e < 4; ++e)
            w[e] = (u32)hb[q * 8 + 2 * e] | ((u32)hb[q * 8 + 2 * e + 1] << 16);
        *reinterpret_cast<uint4*>(T + base + q * 8) = make_uint4(w[0], w[1], w[2], w[3]);
    }
    if (z == 3) {
#pragma unroll
        for (int q = 0; q < 2; ++q) {
            u32 w[4];
#pragma unroll
            for (int e = 0; e < 4; ++e)
                w[e] = (u32)lb[q * 8 + 2 * e] | ((u32)lb[q * 8 + 2 * e + 1] << 16);
            *reinterpret_cast<uint4*>(T3lo + base + q * 8) = make_uint4(w[0], w[1], w[2], w[3]);
        }
    }
}

// ---------------- MFMA GEMM: Y[M,N] = A[M,K] @ Bt[N,K]^T + bias ----------------
// NPROD=1: Ah*Bh.  NPROD=3: Ah*Bh + Ah*Bl + Al*Bh (bf16 hi/lo ~ fp32 accuracy).
// Block = 128 x (NFN*32) with 4 waves (2x2), wave tile 64 x (NFN*16).
template<int NPROD, int NFN, bool OUTBF>
__global__ __launch_bounds__(256, NPROD == 1 ? 3 : 2)
void mfma_gemm(const u16* __restrict__ Ah, const u16* __restrict__ Al,
               const u16* __restrict__ B0, const u16* __restrict__ B1,
               const u16* __restrict__ B2, const u16* __restrict__ Bl,
               const float* __restrict__ bias0, const float* __restrict__ bias1,
               const float* __restrict__ bias2,
               void* __restrict__ Y0, void* __restrict__ Y1, void* __restrict__ Y2,
               int M, int N, int K)
{
    constexpr int TNB = NFN * 32;          // block cols (128 or 64)
    constexpr int LDT = 40;                // LDS row stride (u16); 80B rows

    const int z = blockIdx.z;
    const u16*   Bt   = (z == 0) ? B0 : (z == 1) ? B1 : B2;
    const float* bias = (z == 0) ? bias0 : (z == 1) ? bias1 : bias2;
    void*        Y    = (z == 0) ? Y0 : (z == 1) ? Y1 : Y2;

    __shared__ u16 lds[(NPROD == 3 ? 2 : 1) * (128 + TNB) * LDT];
    u16* lA  = lds;
    u16* lB  = lds + 128 * LDT;
    u16* lA2 = lds + (128 + TNB) * LDT;
    u16* lB2 = lA2 + 128 * LDT;

    const int tid  = threadIdx.x;
    const int wid  = tid >> 6, lane = tid & 63;
    const int wr   = wid >> 1, wc = wid & 1;
    const int lr   = lane & 15, lg = lane >> 4;
    const int bm   = blockIdx.y * 128, bn = blockIdx.x * TNB;

    f32x4 acc[4][NFN];
#pragma unroll
    for (int i = 0; i < 4; ++i)
#pragma unroll
        for (int j = 0; j < NFN; ++j) acc[i][j] = (f32x4)0.0f;

    for (int k0 = 0; k0 < K; k0 += 32) {
        // stage A tiles (128 rows x 32)
#pragma unroll
        for (int g = tid; g < 512; g += 256) {
            int row = g >> 2, gr = g & 3;
            size_t src = (size_t)(bm + row) * K + k0 + gr * 8;
            *reinterpret_cast<uint4*>(lA + row * LDT + gr * 8) =
                *reinterpret_cast<const uint4*>(Ah + src);
            if (NPROD == 3)
                *reinterpret_cast<uint4*>(lA2 + row * LDT + gr * 8) =
                    *reinterpret_cast<const uint4*>(Al + src);
        }
        // stage B tiles (TNB rows x 32)
#pragma unroll
        for (int g = tid; g < TNB * 4; g += 256) {
            int row = g >> 2, gr = g & 3;
            size_t src = (size_t)(bn + row) * K + k0 + gr * 8;
            *reinterpret_cast<uint4*>(lB + row * LDT + gr * 8) =
                *reinterpret_cast<const uint4*>(Bt + src);
            if (NPROD == 3)
                *reinterpret_cast<uint4*>(lB2 + row * LDT + gr * 8) =
                    *reinterpret_cast<const uint4*>(Bl + src);
        }
        __syncthreads();

        bf16x8 a0[4], a1[4], b0[NFN], b1[NFN];
#pragma unroll
        for (int mf = 0; mf < 4; ++mf) {
            int off = (wr * 64 + mf * 16 + lr) * LDT + lg * 8;
            a0[mf] = *reinterpret_cast<const bf16x8*>(lA + off);
            if (NPROD == 3) a1[mf] = *reinterpret_cast<const bf16x8*>(lA2 + off);
        }
#pragma unroll
        for (int nf = 0; nf < NFN; ++nf) {
            int off = (wc * NFN * 16 + nf * 16 + lr) * LDT + lg * 8;
            b0[nf] = *reinterpret_cast<const bf16x8*>(lB + off);
            if (NPROD == 3) b1[nf] = *reinterpret_cast<const bf16x8*>(lB2 + off);
        }
#pragma unroll
        for (int mf = 0; mf < 4; ++mf)
#pragma unroll
            for (int nf = 0; nf < NFN; ++nf) {
                acc[mf][nf] = __builtin_amdgcn_mfma_f32_16x16x32_bf16(
                    a0[mf], b0[nf], acc[mf][nf], 0, 0, 0);
                if (NPROD == 3) {
                    acc[mf][nf] = __builtin_amdgcn_mfma_f32_16x16x32_bf16(
                        a0[mf], b1[nf], acc[mf][nf], 0, 0, 0);
                    acc[mf][nf] = __builtin_amdgcn_mfma_f32_16x16x32_bf16(
                        a1[mf], b0[nf], acc[mf][nf], 0, 0, 0);
                }
            }
        __syncthreads();
    }

    // epilogue: C/D layout col=lane&15, row=(lane>>4)*4+reg  [m89/m91]
#pragma unroll
    for (int nf = 0; nf < NFN; ++nf) {
        int col = bn + wc * NFN * 16 + nf * 16 + lr;
        float bs = bias[col];
#pragma unroll
        for (int mf = 0; mf < 4; ++mf) {
#pragma unroll
            for (int r = 0; r < 4; ++r) {
                int row = bm + wr * 64 + mf * 16 + lg * 4 + r;
                float val = acc[mf][nf][r] + bs;
                if (OUTBF)
                    ((u16*)Y)[(size_t)row * N + col] = f2bf(val);
                else
                    ((float*)Y)[(size_t)row * N + col] = val;
            }
        }
    }
}

// --------- sliding-window attention: fp32 VALU, bf16 in, bf16 hi/lo out ---------
// 32 q-rows per block, 256 threads, 2x4 micro-tile, 3 blocks/CU.
__global__ __launch_bounds__(256, 3)
void attn_kernel(const u16* __restrict__ Qb, const u16* __restrict__ Kb,
                 const u16* __restrict__ Vb,
                 u16* __restrict__ AOh, u16* __restrict__ AOl)
{
    __shared__ float Qs[64][37];   // [d][r]
    __shared__ float Ks[64][68];   // [d][j]
    __shared__ float Vs[64][68];   // [j][d]
    __shared__ float Ps[64][33];   // [j][r]

    const int qb  = blockIdx.x;          // 0..63
    const int h   = blockIdx.y;
    const int b   = blockIdx.z;
    const int i0  = qb * 32;
    const int tid = threadIdx.x;
    const int ty  = tid >> 4;            // 0..15 -> rows ty*2..+1
    const int tx  = tid & 15;            // cols tx*4..+3
    const int r0  = ty * 2;

    const u16* Kh = Kb + (size_t)b * S_LEN * EMB + (size_t)h * S_LEN * HDIM;

    // stage Q (32 x 64, transposed)
    {
        int r = tid >> 3, d0 = (tid & 7) * 8;
        uint4 u = *reinterpret_cast<const uint4*>(
            Qb + ((size_t)(b * S_LEN + i0 + r)) * EMB + h * HDIM + d0);
        float f[8];
        unpack2(u.x, f[0], f[1]); unpack2(u.y, f[2], f[3]);
        unpack2(u.z, f[4], f[5]); unpack2(u.w, f[6], f[7]);
#pragma unroll
        for (int e = 0; e < 8; ++e) Qs[d0 + e][r] = f[e];
    }

    float m[2] = {-1e30f, -1e30f}, l[2] = {0.f, 0.f};
    float o[2][4];
#pragma unroll
    for (int i = 0; i < 2; ++i)
#pragma unroll
        for (int j = 0; j < 4; ++j) o[i][j] = 0.f;

    int tlo = (i0 - WIN) < 0 ? 0 : (i0 - WIN) >> 6;
    int thi = (i0 + WIN + 31) >> 6;
    if (thi > S_LEN / 64 - 1) thi = S_LEN / 64 - 1;

    for (int t = tlo; t <= thi; ++t) {
        // stage K transposed + V
        {
            int j = tid >> 2, d0 = (tid & 3) * 16;
            const u16* ks = Kh + (size_t)(t * 64 + j) * HDIM + d0;
            uint4 u0 = *reinterpret_cast<const uint4*>(ks);
            uint4 u1 = *reinterpret_cast<const uint4*>(ks + 8);
            float f[16];
            unpack2(u0.x, f[0], f[1]);  unpack2(u0.y, f[2], f[3]);
            unpack2(u0.z, f[4], f[5]);  unpack2(u0.w, f[6], f[7]);
            unpack2(u1.x, f[8], f[9]);  unpack2(u1.y, f[10], f[11]);
            unpack2(u1.z, f[12], f[13]); unpack2(u1.w, f[14], f[15]);
#pragma unroll
            for (int e = 0; e < 16; ++e) Ks[d0 + e][j] = f[e];

            const u16* vs = Vb + ((size_t)(b * S_LEN + t * 64 + j)) * EMB + h * HDIM + d0;
            u0 = *reinterpret_cast<const uint4*>(vs);
            u1 = *reinterpret_cast<const uint4*>(vs + 8);
            unpack2(u0.x, f[0], f[1]);  unpack2(u0.y, f[2], f[3]);
            unpack2(u0.z, f[4], f[5]);  unpack2(u0.w, f[6], f[7]);
            unpack2(u1.x, f[8], f[9]);  unpack2(u1.y, f[10], f[11]);
            unpack2(u1.z, f[12], f[13]); unpack2(u1.w, f[14], f[15]);
#pragma unroll
            for (int q = 0; q < 4; ++q)
                *reinterpret_cast<float4*>(&Vs[j][d0 + 4 * q]) =
                    make_float4(f[4 * q], f[4 * q + 1], f[4 * q + 2], f[4 * q + 3]);
        }
        __syncthreads();

        // QK^T
        float s[2][4];
#pragma unroll
        for (int i = 0; i < 2; ++i)
#pragma unroll
            for (int j = 0; j < 4; ++j) s[i][j] = 0.f;
#pragma unroll 8
        for (int d = 0; d < 64; ++d) {
            float q0 = Qs[d][r0], q1 = Qs[d][r0 + 1];
            float4 kv = *reinterpret_cast<const float4*>(&Ks[d][tx * 4]);
            s[0][0] = fmaf(q0, kv.x, s[0][0]); s[0][1] = fmaf(q0, kv.y, s[0][1]);
            s[0][2] = fmaf(q0, kv.z, s[0][2]); s[0][3] = fmaf(q0, kv.w, s[0][3]);
            s[1][0] = fmaf(q1, kv.x, s[1][0]); s[1][1] = fmaf(q1, kv.y, s[1][1]);
            s[1][2] = fmaf(q1, kv.z, s[1][2]); s[1][3] = fmaf(q1, kv.w, s[1][3]);
        }

        // mask + scale + row max
        float tmax[2] = {-1e30f, -1e30f};
#pragma unroll
        for (int i = 0; i < 2; ++i) {
            int ig = i0 + r0 + i;
#pragma unroll
            for (int j = 0; j < 4; ++j) {
                int jg = t * 64 + tx * 4 + j;
                bool ok = (jg >= ig - WIN) && (jg < ig + WIN);
                float v = ok ? s[i][j] * 0.125f : -1e30f;
                s[i][j] = v;
                tmax[i] = fmaxf(tmax[i], v);
            }
        }
#pragma unroll
        for (int off = 1; off < 16; off <<= 1) {
            tmax[0] = fmaxf(tmax[0], __shfl_xor(tmax[0], off));
            tmax[1] = fmaxf(tmax[1], __shfl_xor(tmax[1], off));
        }

        float sc[2], ps[2];
#pragma unroll
        for (int i = 0; i < 2; ++i) {
            float mn = fmaxf(m[i], tmax[i]);
            sc[i] = __expf(m[i] - mn);
            m[i] = mn;
            float acc = 0.f;
#pragma unroll
            for (int j = 0; j < 4; ++j) {
                float p = __expf(s[i][j] - mn);
                s[i][j] = p;
                acc += p;
            }
            ps[i] = acc;
        }
#pragma unroll
        for (int off = 1; off < 16; off <<= 1) {
            ps[0] += __shfl_xor(ps[0], off);
            ps[1] += __shfl_xor(ps[1], off);
        }
#pragma unroll
        for (int i = 0; i < 2; ++i) {
            l[i] = l[i] * sc[i] + ps[i];
#pragma unroll
            for (int j = 0; j < 4; ++j) o[i][j] *= sc[i];
        }

        // P^T to LDS
#pragma unroll
        for (int i = 0; i < 2; ++i)
#pragma unroll
            for (int j = 0; j < 4; ++j)
                Ps[tx * 4 + j][r0 + i] = s[i][j];
        __syncthreads();

        // PV
#pragma unroll 8
        for (int j = 0; j < 64; ++j) {
            float p0 = Ps[j][r0], p1 = Ps[j][r0 + 1];
            float4 vv = *reinterpret_cast<const float4*>(&Vs[j][tx * 4]);
            o[0][0] = fmaf(p0, vv.x, o[0][0]); o[0][1] = fmaf(p0, vv.y, o[0][1]);
            o[0][2] = fmaf(p0, vv.z, o[0][2]); o[0][3] = fmaf(p0, vv.w, o[0][3]);
            o[1][0] = fmaf(p1, vv.x, o[1][0]); o[1][1] = fmaf(p1, vv.y, o[1][1]);
            o[1][2] = fmaf(p1, vv.z, o[1][2]); o[1][3] = fmaf(p1, vv.w, o[1][3]);
        }
        __syncthreads();
    }

    // normalize, hi/lo split, store
#pragma unroll
    for (int i = 0; i < 2; ++i) {
        float inv = 1.0f / l[i];
        u16x4 hv, lv;
#pragma unroll
        for (int j = 0; j < 4; ++j) {
            float v = o[i][j] * inv;
            hv[j] = f2bf(v);
            lv[j] = f2bf(v - bf2f(hv[j]));
        }
        size_t idx = ((size_t)(b * S_LEN + i0 + r0 + i)) * EMB + h * HDIM + tx * 4;
        *reinterpret_cast<u16x4*>(AOh + idx) = hv;
        *reinterpret_cast<u16x4*>(AOl + idx) = lv;
    }
}

extern "C" void kernel_launch(void* const* d_in, const int* in_sizes, int n_in,
                              void* d_out, int out_size, void* d_ws, size_t ws_size,
                              hipStream_t stream)
{
    (void)n_in; (void)out_size; (void)ws_size;
    const float* x  = (const float*)d_in[0];
    const float* Wq = (const float*)d_in[1];
    const float* bq = (const float*)d_in[2];
    const float* Wk = (const float*)d_in[3];
    const float* bk = (const float*)d_in[4];
    const float* Wv = (const float*)d_in[5];
    const float* bv = (const float*)d_in[6];
    const float* Wo = (const float*)d_in[7];
    const float* bo = (const float*)d_in[8];
    float* out = (float*)d_out;

    const int B = in_sizes[0] / (S_LEN * EMB);
    const int M = B * S_LEN;

    u16* xh   = (u16*)d_ws;
    u16* WtQ  = xh  + (size_t)M * EMB;
    u16* WtK  = WtQ + (size_t)EMB * EMB;
    u16* WtV  = WtK + (size_t)EMB * EMB;
    u16* WtO  = WtV + (size_t)EMB * EMB;
    u16* WtOl = WtO + (size_t)EMB * EMB;
    u16* Qb   = WtOl + (size_t)EMB * EMB;
    u16* Kb   = Qb + (size_t)M * EMB;
    u16* Vb   = Kb + (size_t)M * EMB;
    u16* AOh  = Vb + (size_t)M * EMB;
    u16* AOl  = AOh + (size_t)M * EMB;

    // 1) x -> bf16
    int n4 = M * EMB / 4;
    convert_bf16_kernel<<<n4 / 256, 256, 0, stream>>>(x, xh, n4);

    // 2) W -> W^T bf16 (hi for all, lo for Wo)
    dim3 gt(EMB / 64, EMB / 64, 4);
    transpose_w_kernel<<<gt, 256, 0, stream>>>(Wq, Wk, Wv, Wo, WtQ, WtK, WtV, WtO, WtOl);

    // 3) QKV projections (single bf16 MFMA) -> bf16
    dim3 g1(EMB / 128, M / 128, 3);
    mfma_gemm<1, 4, true><<<g1, 256, 0, stream>>>(
        xh, nullptr, WtQ, WtK, WtV, nullptr, bq, bk, bv, Qb, Kb, Vb, M, EMB, EMB);

    // 4) sliding-window attention -> AO hi/lo bf16
    dim3 g2(S_LEN / 32, HEADS, B);
    attn_kernel<<<g2, 256, 0, stream>>>(Qb, Kb, Vb, AOh, AOl);

    // 5) output projection (3-product hi/lo bf16 ~ fp32) -> f32 out
    dim3 g3(EMB / 64, M / 128, 1);
    mfma_gemm<3, 2, false><<<g3, 256, 0, stream>>>(
        AOh, AOl, WtO, WtO, WtO, WtOl, bo, bo, bo, out, out, out, M, EMB, EMB);
}

// Round 3
// 150.883 us; speedup vs baseline: 5.9391x; 2.0288x over previous
//
#include <hip/hip_runtime.h>

#define S_LEN 2048
#define EMB   1024
#define HEADS 16
#define HDIM  64
#define WIN   256

typedef unsigned short u16;
typedef unsigned int   u32;
typedef float  f32x4  __attribute__((ext_vector_type(4)));
typedef __bf16 bf16x8 __attribute__((ext_vector_type(8)));
typedef unsigned short u16x4 __attribute__((ext_vector_type(4)));

__device__ __forceinline__ u16 f2bf(float v) {            // RNE f32->bf16
    u32 x = __builtin_bit_cast(u32, v);
    return (u16)((x + 0x7fffu + ((x >> 16) & 1u)) >> 16);
}
__device__ __forceinline__ float bf2f(u16 v) {
    u32 x = ((u32)v) << 16;
    return __builtin_bit_cast(float, x);
}

// ---------------- x (f32) -> bf16 ----------------
__global__ void convert_bf16_kernel(const float* __restrict__ in,
                                    u16* __restrict__ out, int n4)
{
    int i = blockIdx.x * blockDim.x + threadIdx.x;
    if (i >= n4) return;
    float4 v = reinterpret_cast<const float4*>(in)[i];
    u16x4 o;
    o[0] = f2bf(v.x); o[1] = f2bf(v.y); o[2] = f2bf(v.z); o[3] = f2bf(v.w);
    reinterpret_cast<u16x4*>(out)[i] = o;
}

// ------------- W[k][n] f32 -> Wt[n][k] bf16 (+lo for z==3) -------------
__global__ __launch_bounds__(256)
void transpose_w_kernel(const float* __restrict__ W0, const float* __restrict__ W1,
                        const float* __restrict__ W2, const float* __restrict__ W3,
                        u16* __restrict__ T0, u16* __restrict__ T1,
                        u16* __restrict__ T2, u16* __restrict__ T3,
                        u16* __restrict__ T3lo)
{
    const int z = blockIdx.z;
    const float* W = (z == 0) ? W0 : (z == 1) ? W1 : (z == 2) ? W2 : W3;
    u16* T = (z == 0) ? T0 : (z == 1) ? T1 : (z == 2) ? T2 : T3;

    __shared__ float Ts[64][68];
    const int tid = threadIdx.x;
    const int k0 = blockIdx.x * 64, n0 = blockIdx.y * 64;

    int r = tid >> 2, c0 = (tid & 3) * 16;
#pragma unroll
    for (int q = 0; q < 4; ++q) {
        float4 v = *reinterpret_cast<const float4*>(W + (size_t)(k0 + r) * EMB + n0 + c0 + 4 * q);
        *reinterpret_cast<float4*>(&Ts[r][c0 + 4 * q]) = v;
    }
    __syncthreads();

    int n = tid >> 2, kk0 = (tid & 3) * 16;
    u16 hb[16], lb[16];
#pragma unroll
    for (int e = 0; e < 16; ++e) {
        float f = Ts[kk0 + e][n];
        hb[e] = f2bf(f);
        lb[e] = f2bf(f - bf2f(hb[e]));
    }
    size_t base = (size_t)(n0 + n) * EMB + k0 + kk0;
#pragma unroll
    for (int q = 0; q < 2; ++q) {
        u32 w[4];
#pragma unroll
        for (int e = 0; e < 4; ++e)
            w[e] = (u32)hb[q * 8 + 2 * e] | ((u32)hb[q * 8 + 2 * e + 1] << 16);
        *reinterpret_cast<uint4*>(T + base + q * 8) = make_uint4(w[0], w[1], w[2], w[3]);
    }
    if (z == 3) {
#pragma unroll
        for (int q = 0; q < 2; ++q) {
            u32 w[4];
#pragma unroll
            for (int e = 0; e < 4; ++e)
                w[e] = (u32)lb[q * 8 + 2 * e] | ((u32)lb[q * 8 + 2 * e + 1] << 16);
            *reinterpret_cast<uint4*>(T3lo + base + q * 8) = make_uint4(w[0], w[1], w[2], w[3]);
        }
    }
}

// ---------------- MFMA GEMM: Y[M,N] = A[M,K] @ Bt[N,K]^T + bias ----------------
template<int NPROD, int NFN, bool OUTBF>
__global__ __launch_bounds__(256, NPROD == 1 ? 3 : 2)
void mfma_gemm(const u16* __restrict__ Ah, const u16* __restrict__ Al,
               const u16* __restrict__ B0, const u16* __restrict__ B1,
               const u16* __restrict__ B2, const u16* __restrict__ Bl,
               const float* __restrict__ bias0, const float* __restrict__ bias1,
               const float* __restrict__ bias2,
               void* __restrict__ Y0, void* __restrict__ Y1, void* __restrict__ Y2,
               int M, int N, int K)
{
    constexpr int TNB = NFN * 32;
    constexpr int LDT = 40;

    const int z = blockIdx.z;
    const u16*   Bt   = (z == 0) ? B0 : (z == 1) ? B1 : B2;
    const float* bias = (z == 0) ? bias0 : (z == 1) ? bias1 : bias2;
    void*        Y    = (z == 0) ? Y0 : (z == 1) ? Y1 : Y2;

    __shared__ u16 lds[(NPROD == 3 ? 2 : 1) * (128 + TNB) * LDT];
    u16* lA  = lds;
    u16* lB  = lds + 128 * LDT;
    u16* lA2 = lds + (128 + TNB) * LDT;
    u16* lB2 = lA2 + 128 * LDT;

    const int tid  = threadIdx.x;
    const int wid  = tid >> 6, lane = tid & 63;
    const int wr   = wid >> 1, wc = wid & 1;
    const int lr   = lane & 15, lg = lane >> 4;
    const int bm   = blockIdx.y * 128, bn = blockIdx.x * TNB;

    f32x4 acc[4][NFN];
#pragma unroll
    for (int i = 0; i < 4; ++i)
#pragma unroll
        for (int j = 0; j < NFN; ++j) acc[i][j] = (f32x4)0.0f;

    for (int k0 = 0; k0 < K; k0 += 32) {
#pragma unroll
        for (int g = tid; g < 512; g += 256) {
            int row = g >> 2, gr = g & 3;
            size_t src = (size_t)(bm + row) * K + k0 + gr * 8;
            *reinterpret_cast<uint4*>(lA + row * LDT + gr * 8) =
                *reinterpret_cast<const uint4*>(Ah + src);
            if (NPROD == 3)
                *reinterpret_cast<uint4*>(lA2 + row * LDT + gr * 8) =
                    *reinterpret_cast<const uint4*>(Al + src);
        }
#pragma unroll
        for (int g = tid; g < TNB * 4; g += 256) {
            int row = g >> 2, gr = g & 3;
            size_t src = (size_t)(bn + row) * K + k0 + gr * 8;
            *reinterpret_cast<uint4*>(lB + row * LDT + gr * 8) =
                *reinterpret_cast<const uint4*>(Bt + src);
            if (NPROD == 3)
                *reinterpret_cast<uint4*>(lB2 + row * LDT + gr * 8) =
                    *reinterpret_cast<const uint4*>(Bl + src);
        }
        __syncthreads();

        bf16x8 a0[4], a1[4], b0[NFN], b1[NFN];
#pragma unroll
        for (int mf = 0; mf < 4; ++mf) {
            int off = (wr * 64 + mf * 16 + lr) * LDT + lg * 8;
            a0[mf] = *reinterpret_cast<const bf16x8*>(lA + off);
            if (NPROD == 3) a1[mf] = *reinterpret_cast<const bf16x8*>(lA2 + off);
        }
#pragma unroll
        for (int nf = 0; nf < NFN; ++nf) {
            int off = (wc * NFN * 16 + nf * 16 + lr) * LDT + lg * 8;
            b0[nf] = *reinterpret_cast<const bf16x8*>(lB + off);
            if (NPROD == 3) b1[nf] = *reinterpret_cast<const bf16x8*>(lB2 + off);
        }
#pragma unroll
        for (int mf = 0; mf < 4; ++mf)
#pragma unroll
            for (int nf = 0; nf < NFN; ++nf) {
                acc[mf][nf] = __builtin_amdgcn_mfma_f32_16x16x32_bf16(
                    a0[mf], b0[nf], acc[mf][nf], 0, 0, 0);
                if (NPROD == 3) {
                    acc[mf][nf] = __builtin_amdgcn_mfma_f32_16x16x32_bf16(
                        a0[mf], b1[nf], acc[mf][nf], 0, 0, 0);
                    acc[mf][nf] = __builtin_amdgcn_mfma_f32_16x16x32_bf16(
                        a1[mf], b0[nf], acc[mf][nf], 0, 0, 0);
                }
            }
        __syncthreads();
    }

#pragma unroll
    for (int nf = 0; nf < NFN; ++nf) {
        int col = bn + wc * NFN * 16 + nf * 16 + lr;
        float bs = bias[col];
#pragma unroll
        for (int mf = 0; mf < 4; ++mf) {
#pragma unroll
            for (int r = 0; r < 4; ++r) {
                int row = bm + wr * 64 + mf * 16 + lg * 4 + r;
                float val = acc[mf][nf][r] + bs;
                if (OUTBF)
                    ((u16*)Y)[(size_t)row * N + col] = f2bf(val);
                else
                    ((float*)Y)[(size_t)row * N + col] = val;
            }
        }
    }
}

// --------- sliding-window attention: full MFMA, bf16 in, bf16 hi/lo out ---------
// 4 waves x 16 q-rows (QB=64), KB=64. K in LDS [j][64] XOR-swizzled, V staged
// transposed Vt[d][j], P per-wave private LDS tile (no barrier needed).
__global__ __launch_bounds__(256, 4)
void attn_mfma_kernel(const u16* __restrict__ Qb, const u16* __restrict__ Kb,
                      const u16* __restrict__ Vb,
                      u16* __restrict__ AOh, u16* __restrict__ AOl)
{
    __shared__ u16 Ks[64 * 64];
    __shared__ u16 Vt[64 * 64];
    __shared__ u16 Ps[4 * 16 * 64];

    // XCD-chunked bijective swizzle: 128 consecutive swz-blocks per XCD
    const int nwg = gridDim.x * gridDim.y * gridDim.z;       // 1024 for B=2
    int n  = blockIdx.x + gridDim.x * (blockIdx.y + gridDim.y * blockIdx.z);
    int sw = (n & 7) * (nwg >> 3) + (n >> 3);
    const int qb = sw & 31;
    const int h  = (sw >> 5) & 15;
    const int b  = sw >> 9;

    const int i0  = qb * 64;
    const int tid = threadIdx.x;
    const int wid = tid >> 6, lane = tid & 63;
    const int lr  = lane & 15, lg = lane >> 4;
    const int l7  = lr & 7;

    const u16* Kh = Kb + (size_t)b * S_LEN * EMB + (size_t)h * S_LEN * HDIM;

    // Q fragments in registers: rows i0 + wid*16 + lr, k-chunks lg*8 (+32)
    bf16x8 qa[2];
    {
        const u16* qp = Qb + ((size_t)(b * S_LEN + i0 + wid * 16 + lr)) * EMB
                        + h * HDIM + lg * 8;
        qa[0] = *reinterpret_cast<const bf16x8*>(qp);
        qa[1] = *reinterpret_cast<const bf16x8*>(qp + 32);
    }

    float m[4], l[4];
    f32x4 o[4];
#pragma unroll
    for (int r = 0; r < 4; ++r) { m[r] = -1e30f; l[r] = 0.0f; }
#pragma unroll
    for (int nf = 0; nf < 4; ++nf) o[nf] = (f32x4)0.0f;

    const int tlo = (qb < 4) ? 0 : qb - 4;
    const int thi = (qb > 27) ? 31 : qb + 4;

    for (int t = tlo; t <= thi; ++t) {
        __syncthreads();   // all waves done reading Ks/Vt of prev tile

        // ---- stage K: linear chunks, coalesced; swizzled b128 LDS writes ----
#pragma unroll
        for (int q = 0; q < 2; ++q) {
            int cc = tid + q * 256;           // 0..511
            int j = cc >> 3, g = cc & 7;
            uint4 v = *reinterpret_cast<const uint4*>(
                Kh + (size_t)(t * 64 + j) * HDIM + g * 8);
            *reinterpret_cast<uint4*>(Ks + j * 64 + ((g ^ (j & 7)) << 3)) = v;
        }
        // ---- stage V transposed: Vt[d][j], paired-row b32 writes ----
        {
            int jp = (tid & 31) * 2, dc = tid >> 5;     // dc 0..7 -> d=dc*8..+7
            const u16* vp = Vb + ((size_t)(b * S_LEN + t * 64 + jp)) * EMB
                            + h * HDIM + dc * 8;
            uint4 r0 = *reinterpret_cast<const uint4*>(vp);
            uint4 r1 = *reinterpret_cast<const uint4*>(vp + EMB);
            const u16* e0 = reinterpret_cast<const u16*>(&r0);
            const u16* e1 = reinterpret_cast<const u16*>(&r1);
            int jg = jp >> 3, jl = jp & 7;
#pragma unroll
            for (int e = 0; e < 8; ++e) {
                int d = dc * 8 + e;
                u32 w = (u32)e0[e] | ((u32)e1[e] << 16);
                *reinterpret_cast<u32*>(Vt + d * 64 + ((jg ^ (d & 7)) << 3) + jl) = w;
            }
        }
        __syncthreads();

        // ---- QK^T: S[16q x 64j] per wave ----
        f32x4 s[4];
#pragma unroll
        for (int nf = 0; nf < 4; ++nf) s[nf] = (f32x4)0.0f;
#pragma unroll
        for (int ks = 0; ks < 2; ++ks) {
            int cg = (ks * 4 + lg) ^ l7;
#pragma unroll
            for (int nf = 0; nf < 4; ++nf) {
                bf16x8 kf = *reinterpret_cast<const bf16x8*>(
                    Ks + (nf * 16 + lr) * 64 + (cg << 3));
                s[nf] = __builtin_amdgcn_mfma_f32_16x16x32_bf16(qa[ks], kf, s[nf], 0, 0, 0);
            }
        }

        // ---- mask + scale + online softmax (lane owns q rows lg*4+r) ----
        float tmax[4] = {-1e30f, -1e30f, -1e30f, -1e30f};
#pragma unroll
        for (int nf = 0; nf < 4; ++nf) {
            int jg = t * 64 + nf * 16 + lr;
#pragma unroll
            for (int r = 0; r < 4; ++r) {
                int qg = i0 + wid * 16 + lg * 4 + r;
                bool ok = (jg >= qg - WIN) && (jg < qg + WIN);
                float v = ok ? s[nf][r] * 0.125f : -1e30f;
                s[nf][r] = v;
                tmax[r] = fmaxf(tmax[r], v);
            }
        }
#pragma unroll
        for (int off = 1; off < 16; off <<= 1)
#pragma unroll
            for (int r = 0; r < 4; ++r)
                tmax[r] = fmaxf(tmax[r], __shfl_xor(tmax[r], off));

        float sc[4], ps[4];
#pragma unroll
        for (int r = 0; r < 4; ++r) {
            float mn = fmaxf(m[r], tmax[r]);
            sc[r] = __expf(m[r] - mn);
            m[r] = mn;
            ps[r] = 0.0f;
        }
        // exp in place, accumulate row sums, write P (per-wave private tile)
#pragma unroll
        for (int nf = 0; nf < 4; ++nf) {
#pragma unroll
            for (int r = 0; r < 4; ++r) {
                float p = __expf(s[nf][r] - m[r]);
                ps[r] += p;
                int row = lg * 4 + r;
                Ps[wid * 1024 + row * 64 +
                   (((nf * 2 + (lr >> 3)) ^ (row & 7)) << 3) + l7] = f2bf(p);
            }
        }
#pragma unroll
        for (int off = 1; off < 16; off <<= 1)
#pragma unroll
            for (int r = 0; r < 4; ++r)
                ps[r] += __shfl_xor(ps[r], off);
#pragma unroll
        for (int r = 0; r < 4; ++r) l[r] = l[r] * sc[r] + ps[r];
#pragma unroll
        for (int nf = 0; nf < 4; ++nf)
#pragma unroll
            for (int r = 0; r < 4; ++r) o[nf][r] *= sc[r];

        // ---- PV: O[16q x 64d] += P[16q x 64j] * V[64j x 64d] ----
#pragma unroll
        for (int ks = 0; ks < 2; ++ks) {
            int cg = (ks * 4 + lg) ^ l7;
            bf16x8 pf = *reinterpret_cast<const bf16x8*>(
                Ps + wid * 1024 + lr * 64 + (cg << 3));
#pragma unroll
            for (int nf = 0; nf < 4; ++nf) {
                bf16x8 vf = *reinterpret_cast<const bf16x8*>(
                    Vt + (nf * 16 + lr) * 64 + (cg << 3));
                o[nf] = __builtin_amdgcn_mfma_f32_16x16x32_bf16(pf, vf, o[nf], 0, 0, 0);
            }
        }
    }

    // ---- epilogue: normalize, hi/lo bf16 split, store ----
    float inv[4];
#pragma unroll
    for (int r = 0; r < 4; ++r) inv[r] = 1.0f / l[r];
#pragma unroll
    for (int nf = 0; nf < 4; ++nf) {
#pragma unroll
        for (int r = 0; r < 4; ++r) {
            float v = o[nf][r] * inv[r];
            u16 hb = f2bf(v);
            u16 lb = f2bf(v - bf2f(hb));
            size_t idx = ((size_t)(b * S_LEN + i0 + wid * 16 + lg * 4 + r)) * EMB
                         + h * HDIM + nf * 16 + lr;
            AOh[idx] = hb;
            AOl[idx] = lb;
        }
    }
}

extern "C" void kernel_launch(void* const* d_in, const int* in_sizes, int n_in,
                              void* d_out, int out_size, void* d_ws, size_t ws_size,
                              hipStream_t stream)
{
    (void)n_in; (void)out_size; (void)ws_size;
    const float* x  = (const float*)d_in[0];
    const float* Wq = (const float*)d_in[1];
    const float* bq = (const float*)d_in[2];
    const float* Wk = (const float*)d_in[3];
    const float* bk = (const float*)d_in[4];
    const float* Wv = (const float*)d_in[5];
    const float* bv = (const float*)d_in[6];
    const float* Wo = (const float*)d_in[7];
    const float* bo = (const float*)d_in[8];
    float* out = (float*)d_out;

    const int B = in_sizes[0] / (S_LEN * EMB);
    const int M = B * S_LEN;

    u16* xh   = (u16*)d_ws;
    u16* WtQ  = xh  + (size_t)M * EMB;
    u16* WtK  = WtQ + (size_t)EMB * EMB;
    u16* WtV  = WtK + (size_t)EMB * EMB;
    u16* WtO  = WtV + (size_t)EMB * EMB;
    u16* WtOl = WtO + (size_t)EMB * EMB;
    u16* Qb   = WtOl + (size_t)EMB * EMB;
    u16* Kb   = Qb + (size_t)M * EMB;
    u16* Vb   = Kb + (size_t)M * EMB;
    u16* AOh  = Vb + (size_t)M * EMB;
    u16* AOl  = AOh + (size_t)M * EMB;

    int n4 = M * EMB / 4;
    convert_bf16_kernel<<<n4 / 256, 256, 0, stream>>>(x, xh, n4);

    dim3 gt(EMB / 64, EMB / 64, 4);
    transpose_w_kernel<<<gt, 256, 0, stream>>>(Wq, Wk, Wv, Wo, WtQ, WtK, WtV, WtO, WtOl);

    dim3 g1(EMB / 128, M / 128, 3);
    mfma_gemm<1, 4, true><<<g1, 256, 0, stream>>>(
        xh, nullptr, WtQ, WtK, WtV, nullptr, bq, bk, bv, Qb, Kb, Vb, M, EMB, EMB);

    dim3 g2(S_LEN / 64, HEADS, B);
    attn_mfma_kernel<<<g2, 256, 0, stream>>>(Qb, Kb, Vb, AOh, AOl);

    dim3 g3(EMB / 64, M / 128, 1);
    mfma_gemm<3, 2, false><<<g3, 256, 0, stream>>>(
        AOh, AOl, WtO, WtO, WtO, WtOl, bo, bo, bo, out, out, out, M, EMB, EMB);
}

// Round 4
// 130.222 us; speedup vs baseline: 6.8814x; 1.1587x over previous
//
#include <hip/hip_runtime.h>

#define S_LEN 2048
#define EMB   1024
#define HEADS 16
#define HDIM  64
#define WIN   256

typedef unsigned short u16;
typedef unsigned int   u32;
typedef float  f32x4  __attribute__((ext_vector_type(4)));
typedef __bf16 bf16x8 __attribute__((ext_vector_type(8)));
typedef unsigned short u16x4 __attribute__((ext_vector_type(4)));

__device__ __forceinline__ u16 f2bf(float v) {            // RNE f32->bf16
    u32 x = __builtin_bit_cast(u32, v);
    return (u16)((x + 0x7fffu + ((x >> 16) & 1u)) >> 16);
}

// ---------------- x (f32) -> bf16 ----------------
__global__ void convert_bf16_kernel(const float* __restrict__ in,
                                    u16* __restrict__ out, int n4)
{
    int i = blockIdx.x * blockDim.x + threadIdx.x;
    if (i >= n4) return;
    float4 v = reinterpret_cast<const float4*>(in)[i];
    u16x4 o;
    o[0] = f2bf(v.x); o[1] = f2bf(v.y); o[2] = f2bf(v.z); o[3] = f2bf(v.w);
    reinterpret_cast<u16x4*>(out)[i] = o;
}

// ------------- W[k][n] f32 -> Wt[n][k] bf16 -------------
__global__ __launch_bounds__(256)
void transpose_w_kernel(const float* __restrict__ W0, const float* __restrict__ W1,
                        const float* __restrict__ W2, const float* __restrict__ W3,
                        u16* __restrict__ T0, u16* __restrict__ T1,
                        u16* __restrict__ T2, u16* __restrict__ T3)
{
    const int z = blockIdx.z;
    const float* W = (z == 0) ? W0 : (z == 1) ? W1 : (z == 2) ? W2 : W3;
    u16* T = (z == 0) ? T0 : (z == 1) ? T1 : (z == 2) ? T2 : T3;

    __shared__ float Ts[64][68];
    const int tid = threadIdx.x;
    const int k0 = blockIdx.x * 64, n0 = blockIdx.y * 64;

    int r = tid >> 2, c0 = (tid & 3) * 16;
#pragma unroll
    for (int q = 0; q < 4; ++q) {
        float4 v = *reinterpret_cast<const float4*>(W + (size_t)(k0 + r) * EMB + n0 + c0 + 4 * q);
        *reinterpret_cast<float4*>(&Ts[r][c0 + 4 * q]) = v;
    }
    __syncthreads();

    int n = tid >> 2, kk0 = (tid & 3) * 16;
    u16 hb[16];
#pragma unroll
    for (int e = 0; e < 16; ++e) hb[e] = f2bf(Ts[kk0 + e][n]);
    size_t base = (size_t)(n0 + n) * EMB + k0 + kk0;
#pragma unroll
    for (int q = 0; q < 2; ++q) {
        u32 w[4];
#pragma unroll
        for (int e = 0; e < 4; ++e)
            w[e] = (u32)hb[q * 8 + 2 * e] | ((u32)hb[q * 8 + 2 * e + 1] << 16);
        *reinterpret_cast<uint4*>(T + base + q * 8) = make_uint4(w[0], w[1], w[2], w[3]);
    }
}

// ---------------- MFMA GEMM: Y[M,N] = A[M,K] @ Bt[N,K]^T + bias ----------------
// Block = 128 x (NFN*32) with 4 waves (2x2), wave tile 64 x (NFN*16).
template<int NFN, bool OUTBF>
__global__ __launch_bounds__(256, 3)
void mfma_gemm(const u16* __restrict__ A,
               const u16* __restrict__ B0, const u16* __restrict__ B1,
               const u16* __restrict__ B2,
               const float* __restrict__ bias0, const float* __restrict__ bias1,
               const float* __restrict__ bias2,
               void* __restrict__ Y0, void* __restrict__ Y1, void* __restrict__ Y2,
               int M, int N, int K)
{
    constexpr int TNB = NFN * 32;
    constexpr int LDT = 40;

    const int z = blockIdx.z;
    const u16*   Bt   = (z == 0) ? B0 : (z == 1) ? B1 : B2;
    const float* bias = (z == 0) ? bias0 : (z == 1) ? bias1 : bias2;
    void*        Y    = (z == 0) ? Y0 : (z == 1) ? Y1 : Y2;

    __shared__ u16 lds[(128 + TNB) * LDT];
    u16* lA = lds;
    u16* lB = lds + 128 * LDT;

    const int tid  = threadIdx.x;
    const int wid  = tid >> 6, lane = tid & 63;
    const int wr   = wid >> 1, wc = wid & 1;
    const int lr   = lane & 15, lg = lane >> 4;
    const int bm   = blockIdx.y * 128, bn = blockIdx.x * TNB;

    f32x4 acc[4][NFN];
#pragma unroll
    for (int i = 0; i < 4; ++i)
#pragma unroll
        for (int j = 0; j < NFN; ++j) acc[i][j] = (f32x4)0.0f;

    for (int k0 = 0; k0 < K; k0 += 32) {
#pragma unroll
        for (int g = tid; g < 512; g += 256) {
            int row = g >> 2, gr = g & 3;
            size_t src = (size_t)(bm + row) * K + k0 + gr * 8;
            *reinterpret_cast<uint4*>(lA + row * LDT + gr * 8) =
                *reinterpret_cast<const uint4*>(A + src);
        }
#pragma unroll
        for (int g = tid; g < TNB * 4; g += 256) {
            int row = g >> 2, gr = g & 3;
            size_t src = (size_t)(bn + row) * K + k0 + gr * 8;
            *reinterpret_cast<uint4*>(lB + row * LDT + gr * 8) =
                *reinterpret_cast<const uint4*>(Bt + src);
        }
        __syncthreads();

        bf16x8 a0[4], b0[NFN];
#pragma unroll
        for (int mf = 0; mf < 4; ++mf)
            a0[mf] = *reinterpret_cast<const bf16x8*>(
                lA + (wr * 64 + mf * 16 + lr) * LDT + lg * 8);
#pragma unroll
        for (int nf = 0; nf < NFN; ++nf)
            b0[nf] = *reinterpret_cast<const bf16x8*>(
                lB + (wc * NFN * 16 + nf * 16 + lr) * LDT + lg * 8);
#pragma unroll
        for (int mf = 0; mf < 4; ++mf)
#pragma unroll
            for (int nf = 0; nf < NFN; ++nf)
                acc[mf][nf] = __builtin_amdgcn_mfma_f32_16x16x32_bf16(
                    a0[mf], b0[nf], acc[mf][nf], 0, 0, 0);
        __syncthreads();
    }

    // epilogue: C/D layout col=lane&15, row=(lane>>4)*4+reg  [m89/m91]
#pragma unroll
    for (int nf = 0; nf < NFN; ++nf) {
        int col = bn + wc * NFN * 16 + nf * 16 + lr;
        float bs = bias[col];
#pragma unroll
        for (int mf = 0; mf < 4; ++mf) {
#pragma unroll
            for (int r = 0; r < 4; ++r) {
                int row = bm + wr * 64 + mf * 16 + lg * 4 + r;
                float val = acc[mf][nf][r] + bs;
                if (OUTBF)
                    ((u16*)Y)[(size_t)row * N + col] = f2bf(val);
                else
                    ((float*)Y)[(size_t)row * N + col] = val;
            }
        }
    }
}

// --------- sliding-window attention: full MFMA, bf16 in/out ---------
// 4 waves x 16 q-rows (QB=64), KB=64. K in LDS [j][64] XOR-swizzled, V staged
// transposed Vt[d][j], P per-wave private LDS tile (no barrier needed).
__global__ __launch_bounds__(256, 4)
void attn_mfma_kernel(const u16* __restrict__ Qb, const u16* __restrict__ Kb,
                      const u16* __restrict__ Vb, u16* __restrict__ AOh)
{
    __shared__ u16 Ks[64 * 64];
    __shared__ u16 Vt[64 * 64];
    __shared__ u16 Ps[4 * 16 * 64];

    // XCD-chunked bijective swizzle: 128 consecutive swz-blocks per XCD
    const int nwg = gridDim.x * gridDim.y * gridDim.z;       // 1024 for B=2
    int n  = blockIdx.x + gridDim.x * (blockIdx.y + gridDim.y * blockIdx.z);
    int sw = (n & 7) * (nwg >> 3) + (n >> 3);
    const int qb = sw & 31;
    const int h  = (sw >> 5) & 15;
    const int b  = sw >> 9;

    const int i0  = qb * 64;
    const int tid = threadIdx.x;
    const int wid = tid >> 6, lane = tid & 63;
    const int lr  = lane & 15, lg = lane >> 4;
    const int l7  = lr & 7;

    const u16* Kh = Kb + (size_t)b * S_LEN * EMB + (size_t)h * S_LEN * HDIM;

    // Q fragments in registers: rows i0 + wid*16 + lr, k-chunks lg*8 (+32)
    bf16x8 qa[2];
    {
        const u16* qp = Qb + ((size_t)(b * S_LEN + i0 + wid * 16 + lr)) * EMB
                        + h * HDIM + lg * 8;
        qa[0] = *reinterpret_cast<const bf16x8*>(qp);
        qa[1] = *reinterpret_cast<const bf16x8*>(qp + 32);
    }

    float m[4], l[4];
    f32x4 o[4];
#pragma unroll
    for (int r = 0; r < 4; ++r) { m[r] = -1e30f; l[r] = 0.0f; }
#pragma unroll
    for (int nf = 0; nf < 4; ++nf) o[nf] = (f32x4)0.0f;

    const int tlo = (qb < 4) ? 0 : qb - 4;
    const int thi = (qb > 27) ? 31 : qb + 4;

    for (int t = tlo; t <= thi; ++t) {
        __syncthreads();   // all waves done reading Ks/Vt of prev tile

        // ---- stage K: linear chunks, coalesced; swizzled b128 LDS writes ----
#pragma unroll
        for (int q = 0; q < 2; ++q) {
            int cc = tid + q * 256;           // 0..511
            int j = cc >> 3, g = cc & 7;
            uint4 v = *reinterpret_cast<const uint4*>(
                Kh + (size_t)(t * 64 + j) * HDIM + g * 8);
            *reinterpret_cast<uint4*>(Ks + j * 64 + ((g ^ (j & 7)) << 3)) = v;
        }
        // ---- stage V transposed: Vt[d][j], paired-row b32 writes ----
        {
            int jp = (tid & 31) * 2, dc = tid >> 5;     // dc 0..7 -> d=dc*8..+7
            const u16* vp = Vb + ((size_t)(b * S_LEN + t * 64 + jp)) * EMB
                            + h * HDIM + dc * 8;
            uint4 r0 = *reinterpret_cast<const uint4*>(vp);
            uint4 r1 = *reinterpret_cast<const uint4*>(vp + EMB);
            const u16* e0 = reinterpret_cast<const u16*>(&r0);
            const u16* e1 = reinterpret_cast<const u16*>(&r1);
            int jg = jp >> 3, jl = jp & 7;
#pragma unroll
            for (int e = 0; e < 8; ++e) {
                int d = dc * 8 + e;
                u32 w = (u32)e0[e] | ((u32)e1[e] << 16);
                *reinterpret_cast<u32*>(Vt + d * 64 + ((jg ^ (d & 7)) << 3) + jl) = w;
            }
        }
        __syncthreads();

        // ---- QK^T: S[16q x 64j] per wave ----
        f32x4 s[4];
#pragma unroll
        for (int nf = 0; nf < 4; ++nf) s[nf] = (f32x4)0.0f;
#pragma unroll
        for (int ks = 0; ks < 2; ++ks) {
            int cg = (ks * 4 + lg) ^ l7;
#pragma unroll
            for (int nf = 0; nf < 4; ++nf) {
                bf16x8 kf = *reinterpret_cast<const bf16x8*>(
                    Ks + (nf * 16 + lr) * 64 + (cg << 3));
                s[nf] = __builtin_amdgcn_mfma_f32_16x16x32_bf16(qa[ks], kf, s[nf], 0, 0, 0);
            }
        }

        // ---- mask + scale + online softmax (lane owns q rows lg*4+r) ----
        float tmax[4] = {-1e30f, -1e30f, -1e30f, -1e30f};
#pragma unroll
        for (int nf = 0; nf < 4; ++nf) {
            int jg = t * 64 + nf * 16 + lr;
#pragma unroll
            for (int r = 0; r < 4; ++r) {
                int qg = i0 + wid * 16 + lg * 4 + r;
                bool ok = (jg >= qg - WIN) && (jg < qg + WIN);
                float v = ok ? s[nf][r] * 0.125f : -1e30f;
                s[nf][r] = v;
                tmax[r] = fmaxf(tmax[r], v);
            }
        }
#pragma unroll
        for (int off = 1; off < 16; off <<= 1)
#pragma unroll
            for (int r = 0; r < 4; ++r)
                tmax[r] = fmaxf(tmax[r], __shfl_xor(tmax[r], off));

        // T13 defer-rescale: only touch m/o/l when a row max moved past +8
        bool need = (tmax[0] > m[0] + 8.0f) || (tmax[1] > m[1] + 8.0f) ||
                    (tmax[2] > m[2] + 8.0f) || (tmax[3] > m[3] + 8.0f);
        if (__any(need)) {
#pragma unroll
            for (int r = 0; r < 4; ++r) {
                float mn = fmaxf(m[r], tmax[r]);
                float sc = __expf(m[r] - mn);
                m[r] = mn;
                l[r] *= sc;
#pragma unroll
                for (int nf = 0; nf < 4; ++nf) o[nf][r] *= sc;
            }
        }

        // exp in place, accumulate row sums, write P (per-wave private tile)
        float ps[4] = {0.f, 0.f, 0.f, 0.f};
#pragma unroll
        for (int nf = 0; nf < 4; ++nf) {
#pragma unroll
            for (int r = 0; r < 4; ++r) {
                float p = __expf(s[nf][r] - m[r]);
                ps[r] += p;
                int row = lg * 4 + r;
                Ps[wid * 1024 + row * 64 +
                   (((nf * 2 + (lr >> 3)) ^ (row & 7)) << 3) + l7] = f2bf(p);
            }
        }
#pragma unroll
        for (int off = 1; off < 16; off <<= 1)
#pragma unroll
            for (int r = 0; r < 4; ++r)
                ps[r] += __shfl_xor(ps[r], off);
#pragma unroll
        for (int r = 0; r < 4; ++r) l[r] += ps[r];

        // ---- PV: O[16q x 64d] += P[16q x 64j] * V[64j x 64d] ----
#pragma unroll
        for (int ks = 0; ks < 2; ++ks) {
            int cg = (ks * 4 + lg) ^ l7;
            bf16x8 pf = *reinterpret_cast<const bf16x8*>(
                Ps + wid * 1024 + lr * 64 + (cg << 3));
#pragma unroll
            for (int nf = 0; nf < 4; ++nf) {
                bf16x8 vf = *reinterpret_cast<const bf16x8*>(
                    Vt + (nf * 16 + lr) * 64 + (cg << 3));
                o[nf] = __builtin_amdgcn_mfma_f32_16x16x32_bf16(pf, vf, o[nf], 0, 0, 0);
            }
        }
    }

    // ---- epilogue: normalize, bf16, store ----
    float inv[4];
#pragma unroll
    for (int r = 0; r < 4; ++r) inv[r] = 1.0f / l[r];
#pragma unroll
    for (int nf = 0; nf < 4; ++nf) {
#pragma unroll
        for (int r = 0; r < 4; ++r) {
            size_t idx = ((size_t)(b * S_LEN + i0 + wid * 16 + lg * 4 + r)) * EMB
                         + h * HDIM + nf * 16 + lr;
            AOh[idx] = f2bf(o[nf][r] * inv[r]);
        }
    }
}

extern "C" void kernel_launch(void* const* d_in, const int* in_sizes, int n_in,
                              void* d_out, int out_size, void* d_ws, size_t ws_size,
                              hipStream_t stream)
{
    (void)n_in; (void)out_size; (void)ws_size;
    const float* x  = (const float*)d_in[0];
    const float* Wq = (const float*)d_in[1];
    const float* bq = (const float*)d_in[2];
    const float* Wk = (const float*)d_in[3];
    const float* bk = (const float*)d_in[4];
    const float* Wv = (const float*)d_in[5];
    const float* bv = (const float*)d_in[6];
    const float* Wo = (const float*)d_in[7];
    const float* bo = (const float*)d_in[8];
    float* out = (float*)d_out;

    const int B = in_sizes[0] / (S_LEN * EMB);
    const int M = B * S_LEN;

    u16* xh  = (u16*)d_ws;
    u16* WtQ = xh  + (size_t)M * EMB;
    u16* WtK = WtQ + (size_t)EMB * EMB;
    u16* WtV = WtK + (size_t)EMB * EMB;
    u16* WtO = WtV + (size_t)EMB * EMB;
    u16* Qb  = WtO + (size_t)EMB * EMB;
    u16* Kb  = Qb + (size_t)M * EMB;
    u16* Vb  = Kb + (size_t)M * EMB;
    u16* AOh = Vb + (size_t)M * EMB;

    int n4 = M * EMB / 4;
    convert_bf16_kernel<<<n4 / 256, 256, 0, stream>>>(x, xh, n4);

    dim3 gt(EMB / 64, EMB / 64, 4);
    transpose_w_kernel<<<gt, 256, 0, stream>>>(Wq, Wk, Wv, Wo, WtQ, WtK, WtV, WtO);

    // QKV projections (bf16 MFMA) -> bf16
    dim3 g1(EMB / 128, M / 128, 3);
    mfma_gemm<4, true><<<g1, 256, 0, stream>>>(
        xh, WtQ, WtK, WtV, bq, bk, bv, Qb, Kb, Vb, M, EMB, EMB);

    // sliding-window attention -> AO bf16
    dim3 g2(S_LEN / 64, HEADS, B);
    attn_mfma_kernel<<<g2, 256, 0, stream>>>(Qb, Kb, Vb, AOh);

    // output projection (bf16 MFMA) -> f32 out; NFN=2 for 512 blocks (2/CU)
    dim3 g3(EMB / 64, M / 128, 1);
    mfma_gemm<2, false><<<g3, 256, 0, stream>>>(
        AOh, WtO, WtO, WtO, bo, bo, bo, out, out, out, M, EMB, EMB);
}

// Round 5
// 103.629 us; speedup vs baseline: 8.6473x; 1.2566x over previous
//
#include <hip/hip_runtime.h>

#define S_LEN 2048
#define EMB   1024
#define HEADS 16
#define HDIM  64
#define WIN   256

typedef unsigned short u16;
typedef unsigned int   u32;
typedef float  f32x4  __attribute__((ext_vector_type(4)));
typedef __bf16 bf16x8 __attribute__((ext_vector_type(8)));
typedef unsigned short u16x4 __attribute__((ext_vector_type(4)));

typedef const __attribute__((address_space(1))) u32* gas_ptr;
typedef __attribute__((address_space(3))) u32*       las_ptr;

__device__ __forceinline__ void gload16(const void* g, void* l) {
    // wave-uniform LDS base + lane*16B; per-lane global addr  [m97]
    __builtin_amdgcn_global_load_lds((gas_ptr)g, (las_ptr)l, 16, 0, 0);
}

__device__ __forceinline__ u16 f2bf(float v) {            // RNE f32->bf16
    u32 x = __builtin_bit_cast(u32, v);
    return (u16)((x + 0x7fffu + ((x >> 16) & 1u)) >> 16);
}

// ---------------- x (f32) -> bf16 ----------------
__global__ void convert_bf16_kernel(const float* __restrict__ in,
                                    u16* __restrict__ out, int n4)
{
    int i = blockIdx.x * blockDim.x + threadIdx.x;
    if (i >= n4) return;
    float4 v = reinterpret_cast<const float4*>(in)[i];
    u16x4 o;
    o[0] = f2bf(v.x); o[1] = f2bf(v.y); o[2] = f2bf(v.z); o[3] = f2bf(v.w);
    reinterpret_cast<u16x4*>(out)[i] = o;
}

// ------------- W[k][n] f32 -> Wt[n][k] bf16 -------------
__global__ __launch_bounds__(256)
void transpose_w_kernel(const float* __restrict__ W0, const float* __restrict__ W1,
                        const float* __restrict__ W2, const float* __restrict__ W3,
                        u16* __restrict__ T0, u16* __restrict__ T1,
                        u16* __restrict__ T2, u16* __restrict__ T3)
{
    const int z = blockIdx.z;
    const float* W = (z == 0) ? W0 : (z == 1) ? W1 : (z == 2) ? W2 : W3;
    u16* T = (z == 0) ? T0 : (z == 1) ? T1 : (z == 2) ? T2 : T3;

    __shared__ float Ts[64][68];
    const int tid = threadIdx.x;
    const int k0 = blockIdx.x * 64, n0 = blockIdx.y * 64;

    int r = tid >> 2, c0 = (tid & 3) * 16;
#pragma unroll
    for (int q = 0; q < 4; ++q) {
        float4 v = *reinterpret_cast<const float4*>(W + (size_t)(k0 + r) * EMB + n0 + c0 + 4 * q);
        *reinterpret_cast<float4*>(&Ts[r][c0 + 4 * q]) = v;
    }
    __syncthreads();

    int n = tid >> 2, kk0 = (tid & 3) * 16;
    u16 hb[16];
#pragma unroll
    for (int e = 0; e < 16; ++e) hb[e] = f2bf(Ts[kk0 + e][n]);
    size_t base = (size_t)(n0 + n) * EMB + k0 + kk0;
#pragma unroll
    for (int q = 0; q < 2; ++q) {
        u32 w[4];
#pragma unroll
        for (int e = 0; e < 4; ++e)
            w[e] = (u32)hb[q * 8 + 2 * e] | ((u32)hb[q * 8 + 2 * e + 1] << 16);
        *reinterpret_cast<uint4*>(T + base + q * 8) = make_uint4(w[0], w[1], w[2], w[3]);
    }
}

// ---------------- MFMA GEMM (m97 structure): Y = A @ Bt^T + bias ----------------
// Block = 128 x (NFN*32), 4 waves (2x2). Linear LDS [rows][32] bf16, 64B rows.
// Staging via global_load_lds width=16: chunk = 16 rows x 64B = 1024B/wave-instr.
template<int NFN, bool OUTBF>
__global__ __launch_bounds__(256, 3)
void mfma_gemm(const u16* __restrict__ A,
               const u16* __restrict__ B0, const u16* __restrict__ B1,
               const u16* __restrict__ B2,
               const float* __restrict__ bias0, const float* __restrict__ bias1,
               const float* __restrict__ bias2,
               void* __restrict__ Y0, void* __restrict__ Y1, void* __restrict__ Y2,
               int M, int N, int K)
{
    constexpr int TNB = NFN * 32;

    const int z = blockIdx.z;
    const u16*   Bt   = (z == 0) ? B0 : (z == 1) ? B1 : B2;
    const float* bias = (z == 0) ? bias0 : (z == 1) ? bias1 : bias2;
    void*        Y    = (z == 0) ? Y0 : (z == 1) ? Y1 : Y2;

    __shared__ u16 lds[(128 + TNB) * 32];
    u16* lA = lds;               // [128][32]
    u16* lB = lds + 128 * 32;    // [TNB][32]

    const int tid  = threadIdx.x;
    const int wid  = tid >> 6, lane = tid & 63;
    const int wr   = wid >> 1, wc = wid & 1;
    const int lr   = lane & 15, lg = lane >> 4;
    const int bm   = blockIdx.y * 128, bn = blockIdx.x * TNB;

    // per-lane source coords for global_load_lds chunks
    const int srow = lane >> 2;          // 0..15 within a 16-row chunk
    const int scol = (lane & 3) * 8;     // bf16 col within 32

    f32x4 acc[4][NFN];
#pragma unroll
    for (int i = 0; i < 4; ++i)
#pragma unroll
        for (int j = 0; j < NFN; ++j) acc[i][j] = (f32x4)0.0f;

    for (int k0 = 0; k0 < K; k0 += 32) {
        // A tile: 128x32 = 8 chunks; wave w stages chunks {w, w+4}
#pragma unroll
        for (int q = 0; q < 2; ++q) {
            int ch = wid + q * 4;
            gload16(A + (size_t)(bm + ch * 16 + srow) * K + k0 + scol,
                    lA + ch * 512);
        }
        // B tile: TNB x 32 = TNB/16 chunks
#pragma unroll
        for (int q = 0; q < TNB / 64; ++q) {
            int ch = wid + q * 4;
            gload16(Bt + (size_t)(bn + ch * 16 + srow) * K + k0 + scol,
                    lB + ch * 512);
        }
        __syncthreads();   // compiler drains vmcnt before s_barrier

        bf16x8 a0[4], b0[NFN];
#pragma unroll
        for (int mf = 0; mf < 4; ++mf)
            a0[mf] = *reinterpret_cast<const bf16x8*>(
                lA + (wr * 64 + mf * 16 + lr) * 32 + lg * 8);
#pragma unroll
        for (int nf = 0; nf < NFN; ++nf)
            b0[nf] = *reinterpret_cast<const bf16x8*>(
                lB + (wc * NFN * 16 + nf * 16 + lr) * 32 + lg * 8);
#pragma unroll
        for (int mf = 0; mf < 4; ++mf)
#pragma unroll
            for (int nf = 0; nf < NFN; ++nf)
                acc[mf][nf] = __builtin_amdgcn_mfma_f32_16x16x32_bf16(
                    a0[mf], b0[nf], acc[mf][nf], 0, 0, 0);
        __syncthreads();
    }

    // epilogue: C/D layout col=lane&15, row=(lane>>4)*4+reg  [m89/m91]
#pragma unroll
    for (int nf = 0; nf < NFN; ++nf) {
        int col = bn + wc * NFN * 16 + nf * 16 + lr;
        float bs = bias[col];
#pragma unroll
        for (int mf = 0; mf < 4; ++mf) {
#pragma unroll
            for (int r = 0; r < 4; ++r) {
                int row = bm + wr * 64 + mf * 16 + lg * 4 + r;
                float val = acc[mf][nf][r] + bs;
                if (OUTBF)
                    ((u16*)Y)[(size_t)row * N + col] = f2bf(val);
                else
                    ((float*)Y)[(size_t)row * N + col] = val;
            }
        }
    }
}

// --------- sliding-window attention: full MFMA, bf16 in/out ---------
// 4 waves x 16 q-rows (QB=64), KB=64. K in LDS [j][64] XOR-swizzled, V staged
// transposed Vt[d][j], P per-wave private LDS tile (no barrier needed).
__global__ __launch_bounds__(256, 4)
void attn_mfma_kernel(const u16* __restrict__ Qb, const u16* __restrict__ Kb,
                      const u16* __restrict__ Vb, u16* __restrict__ AOh)
{
    __shared__ u16 Ks[64 * 64];
    __shared__ u16 Vt[64 * 64];
    __shared__ u16 Ps[4 * 16 * 64];

    // XCD-chunked bijective swizzle: 128 consecutive swz-blocks per XCD
    const int nwg = gridDim.x * gridDim.y * gridDim.z;       // 1024 for B=2
    int n  = blockIdx.x + gridDim.x * (blockIdx.y + gridDim.y * blockIdx.z);
    int sw = (n & 7) * (nwg >> 3) + (n >> 3);
    const int qb = sw & 31;
    const int h  = (sw >> 5) & 15;
    const int b  = sw >> 9;

    const int i0  = qb * 64;
    const int tid = threadIdx.x;
    const int wid = tid >> 6, lane = tid & 63;
    const int lr  = lane & 15, lg = lane >> 4;
    const int l7  = lr & 7;

    const u16* Kh = Kb + (size_t)b * S_LEN * EMB + (size_t)h * S_LEN * HDIM;

    // Q fragments in registers: rows i0 + wid*16 + lr, k-chunks lg*8 (+32)
    bf16x8 qa[2];
    {
        const u16* qp = Qb + ((size_t)(b * S_LEN + i0 + wid * 16 + lr)) * EMB
                        + h * HDIM + lg * 8;
        qa[0] = *reinterpret_cast<const bf16x8*>(qp);
        qa[1] = *reinterpret_cast<const bf16x8*>(qp + 32);
    }

    float m[4], l[4];
    f32x4 o[4];
#pragma unroll
    for (int r = 0; r < 4; ++r) { m[r] = -1e30f; l[r] = 0.0f; }
#pragma unroll
    for (int nf = 0; nf < 4; ++nf) o[nf] = (f32x4)0.0f;

    const int tlo = (qb < 4) ? 0 : qb - 4;
    const int thi = (qb > 27) ? 31 : qb + 4;

    for (int t = tlo; t <= thi; ++t) {
        __syncthreads();   // all waves done reading Ks/Vt of prev tile

        // ---- stage K: linear chunks, coalesced; swizzled b128 LDS writes ----
#pragma unroll
        for (int q = 0; q < 2; ++q) {
            int cc = tid + q * 256;           // 0..511
            int j = cc >> 3, g = cc & 7;
            uint4 v = *reinterpret_cast<const uint4*>(
                Kh + (size_t)(t * 64 + j) * HDIM + g * 8);
            *reinterpret_cast<uint4*>(Ks + j * 64 + ((g ^ (j & 7)) << 3)) = v;
        }
        // ---- stage V transposed: Vt[d][j], paired-row b32 writes ----
        {
            int jp = (tid & 31) * 2, dc = tid >> 5;     // dc 0..7 -> d=dc*8..+7
            const u16* vp = Vb + ((size_t)(b * S_LEN + t * 64 + jp)) * EMB
                            + h * HDIM + dc * 8;
            uint4 r0 = *reinterpret_cast<const uint4*>(vp);
            uint4 r1 = *reinterpret_cast<const uint4*>(vp + EMB);
            const u16* e0 = reinterpret_cast<const u16*>(&r0);
            const u16* e1 = reinterpret_cast<const u16*>(&r1);
            int jg = jp >> 3, jl = jp & 7;
#pragma unroll
            for (int e = 0; e < 8; ++e) {
                int d = dc * 8 + e;
                u32 w = (u32)e0[e] | ((u32)e1[e] << 16);
                *reinterpret_cast<u32*>(Vt + d * 64 + ((jg ^ (d & 7)) << 3) + jl) = w;
            }
        }
        __syncthreads();

        // ---- QK^T: S[16q x 64j] per wave ----
        f32x4 s[4];
#pragma unroll
        for (int nf = 0; nf < 4; ++nf) s[nf] = (f32x4)0.0f;
#pragma unroll
        for (int ks = 0; ks < 2; ++ks) {
            int cg = (ks * 4 + lg) ^ l7;
#pragma unroll
            for (int nf = 0; nf < 4; ++nf) {
                bf16x8 kf = *reinterpret_cast<const bf16x8*>(
                    Ks + (nf * 16 + lr) * 64 + (cg << 3));
                s[nf] = __builtin_amdgcn_mfma_f32_16x16x32_bf16(qa[ks], kf, s[nf], 0, 0, 0);
            }
        }

        // ---- mask + scale + online softmax (lane owns q rows lg*4+r) ----
        float tmax[4] = {-1e30f, -1e30f, -1e30f, -1e30f};
#pragma unroll
        for (int nf = 0; nf < 4; ++nf) {
            int jg = t * 64 + nf * 16 + lr;
#pragma unroll
            for (int r = 0; r < 4; ++r) {
                int qg = i0 + wid * 16 + lg * 4 + r;
                bool ok = (jg >= qg - WIN) && (jg < qg + WIN);
                float v = ok ? s[nf][r] * 0.125f : -1e30f;
                s[nf][r] = v;
                tmax[r] = fmaxf(tmax[r], v);
            }
        }
#pragma unroll
        for (int off = 1; off < 16; off <<= 1)
#pragma unroll
            for (int r = 0; r < 4; ++r)
                tmax[r] = fmaxf(tmax[r], __shfl_xor(tmax[r], off));

        // T13 defer-rescale: only touch m/o/l when a row max moved past +8
        bool need = (tmax[0] > m[0] + 8.0f) || (tmax[1] > m[1] + 8.0f) ||
                    (tmax[2] > m[2] + 8.0f) || (tmax[3] > m[3] + 8.0f);
        if (__any(need)) {
#pragma unroll
            for (int r = 0; r < 4; ++r) {
                float mn = fmaxf(m[r], tmax[r]);
                float sc = __expf(m[r] - mn);
                m[r] = mn;
                l[r] *= sc;
#pragma unroll
                for (int nf = 0; nf < 4; ++nf) o[nf][r] *= sc;
            }
        }

        // exp in place, accumulate row sums, write P (per-wave private tile)
        float ps[4] = {0.f, 0.f, 0.f, 0.f};
#pragma unroll
        for (int nf = 0; nf < 4; ++nf) {
#pragma unroll
            for (int r = 0; r < 4; ++r) {
                float p = __expf(s[nf][r] - m[r]);
                ps[r] += p;
                int row = lg * 4 + r;
                Ps[wid * 1024 + row * 64 +
                   (((nf * 2 + (lr >> 3)) ^ (row & 7)) << 3) + l7] = f2bf(p);
            }
        }
#pragma unroll
        for (int off = 1; off < 16; off <<= 1)
#pragma unroll
            for (int r = 0; r < 4; ++r)
                ps[r] += __shfl_xor(ps[r], off);
#pragma unroll
        for (int r = 0; r < 4; ++r) l[r] += ps[r];

        // ---- PV: O[16q x 64d] += P[16q x 64j] * V[64j x 64d] ----
#pragma unroll
        for (int ks = 0; ks < 2; ++ks) {
            int cg = (ks * 4 + lg) ^ l7;
            bf16x8 pf = *reinterpret_cast<const bf16x8*>(
                Ps + wid * 1024 + lr * 64 + (cg << 3));
#pragma unroll
            for (int nf = 0; nf < 4; ++nf) {
                bf16x8 vf = *reinterpret_cast<const bf16x8*>(
                    Vt + (nf * 16 + lr) * 64 + (cg << 3));
                o[nf] = __builtin_amdgcn_mfma_f32_16x16x32_bf16(pf, vf, o[nf], 0, 0, 0);
            }
        }
    }

    // ---- epilogue: normalize, bf16, store ----
    float inv[4];
#pragma unroll
    for (int r = 0; r < 4; ++r) inv[r] = 1.0f / l[r];
#pragma unroll
    for (int nf = 0; nf < 4; ++nf) {
#pragma unroll
        for (int r = 0; r < 4; ++r) {
            size_t idx = ((size_t)(b * S_LEN + i0 + wid * 16 + lg * 4 + r)) * EMB
                         + h * HDIM + nf * 16 + lr;
            AOh[idx] = f2bf(o[nf][r] * inv[r]);
        }
    }
}

extern "C" void kernel_launch(void* const* d_in, const int* in_sizes, int n_in,
                              void* d_out, int out_size, void* d_ws, size_t ws_size,
                              hipStream_t stream)
{
    (void)n_in; (void)out_size; (void)ws_size;
    const float* x  = (const float*)d_in[0];
    const float* Wq = (const float*)d_in[1];
    const float* bq = (const float*)d_in[2];
    const float* Wk = (const float*)d_in[3];
    const float* bk = (const float*)d_in[4];
    const float* Wv = (const float*)d_in[5];
    const float* bv = (const float*)d_in[6];
    const float* Wo = (const float*)d_in[7];
    const float* bo = (const float*)d_in[8];
    float* out = (float*)d_out;

    const int B = in_sizes[0] / (S_LEN * EMB);
    const int M = B * S_LEN;

    u16* xh  = (u16*)d_ws;
    u16* WtQ = xh  + (size_t)M * EMB;
    u16* WtK = WtQ + (size_t)EMB * EMB;
    u16* WtV = WtK + (size_t)EMB * EMB;
    u16* WtO = WtV + (size_t)EMB * EMB;
    u16* Qb  = WtO + (size_t)EMB * EMB;
    u16* Kb  = Qb + (size_t)M * EMB;
    u16* Vb  = Kb + (size_t)M * EMB;
    u16* AOh = Vb + (size_t)M * EMB;

    int n4 = M * EMB / 4;
    convert_bf16_kernel<<<n4 / 256, 256, 0, stream>>>(x, xh, n4);

    dim3 gt(EMB / 64, EMB / 64, 4);
    transpose_w_kernel<<<gt, 256, 0, stream>>>(Wq, Wk, Wv, Wo, WtQ, WtK, WtV, WtO);

    // QKV projections (bf16 MFMA, global_load_lds staging) -> bf16
    dim3 g1(EMB / 128, M / 128, 3);
    mfma_gemm<4, true><<<g1, 256, 0, stream>>>(
        xh, WtQ, WtK, WtV, bq, bk, bv, Qb, Kb, Vb, M, EMB, EMB);

    // sliding-window attention -> AO bf16
    dim3 g2(S_LEN / 64, HEADS, B);
    attn_mfma_kernel<<<g2, 256, 0, stream>>>(Qb, Kb, Vb, AOh);

    // output projection -> f32 out; NFN=2 for 512 blocks (2/CU)
    dim3 g3(EMB / 64, M / 128, 1);
    mfma_gemm<2, false><<<g3, 256, 0, stream>>>(
        AOh, WtO, WtO, WtO, bo, bo, bo, out, out, out, M, EMB, EMB);
}

// Round 6
// 92.200 us; speedup vs baseline: 9.7193x; 1.1240x over previous
//
#include <hip/hip_runtime.h>

#define S_LEN 2048
#define EMB   1024
#define HEADS 16
#define HDIM  64
#define WIN   256

typedef unsigned short u16;
typedef unsigned int   u32;
typedef float  f32x4  __attribute__((ext_vector_type(4)));
typedef __bf16 bf16x8 __attribute__((ext_vector_type(8)));
typedef unsigned short u16x4 __attribute__((ext_vector_type(4)));

typedef const __attribute__((address_space(1))) u32* gas_ptr;
typedef __attribute__((address_space(3))) u32*       las_ptr;

__device__ __forceinline__ void gload16(const void* g, void* l) {
    // wave-uniform LDS base + lane*16B; per-lane global addr  [m97]
    __builtin_amdgcn_global_load_lds((gas_ptr)g, (las_ptr)l, 16, 0, 0);
}

__device__ __forceinline__ u16 f2bf(float v) {            // RNE f32->bf16
    u32 x = __builtin_bit_cast(u32, v);
    return (u16)((x + 0x7fffu + ((x >> 16) & 1u)) >> 16);
}
__device__ __forceinline__ u32 cvt_pk_bf16(float lo, float hi) {
    u32 r;
    asm volatile("v_cvt_pk_bf16_f32 %0, %1, %2" : "=v"(r) : "v"(lo), "v"(hi));
    return r;
}

// ---------------- x (f32) -> bf16 ----------------
__global__ void convert_bf16_kernel(const float* __restrict__ in,
                                    u16* __restrict__ out, int n4)
{
    int i = blockIdx.x * blockDim.x + threadIdx.x;
    if (i >= n4) return;
    float4 v = reinterpret_cast<const float4*>(in)[i];
    u16x4 o;
    o[0] = f2bf(v.x); o[1] = f2bf(v.y); o[2] = f2bf(v.z); o[3] = f2bf(v.w);
    reinterpret_cast<u16x4*>(out)[i] = o;
}

// ------------- W[k][n] f32 -> Wt[n][k] bf16 -------------
__global__ __launch_bounds__(256)
void transpose_w_kernel(const float* __restrict__ W0, const float* __restrict__ W1,
                        const float* __restrict__ W2, const float* __restrict__ W3,
                        u16* __restrict__ T0, u16* __restrict__ T1,
                        u16* __restrict__ T2, u16* __restrict__ T3)
{
    const int z = blockIdx.z;
    const float* W = (z == 0) ? W0 : (z == 1) ? W1 : (z == 2) ? W2 : W3;
    u16* T = (z == 0) ? T0 : (z == 1) ? T1 : (z == 2) ? T2 : T3;

    __shared__ float Ts[64][68];
    const int tid = threadIdx.x;
    const int k0 = blockIdx.x * 64, n0 = blockIdx.y * 64;

    int r = tid >> 2, c0 = (tid & 3) * 16;
#pragma unroll
    for (int q = 0; q < 4; ++q) {
        float4 v = *reinterpret_cast<const float4*>(W + (size_t)(k0 + r) * EMB + n0 + c0 + 4 * q);
        *reinterpret_cast<float4*>(&Ts[r][c0 + 4 * q]) = v;
    }
    __syncthreads();

    int n = tid >> 2, kk0 = (tid & 3) * 16;
    u16 hb[16];
#pragma unroll
    for (int e = 0; e < 16; ++e) hb[e] = f2bf(Ts[kk0 + e][n]);
    size_t base = (size_t)(n0 + n) * EMB + k0 + kk0;
#pragma unroll
    for (int q = 0; q < 2; ++q) {
        u32 w[4];
#pragma unroll
        for (int e = 0; e < 4; ++e)
            w[e] = (u32)hb[q * 8 + 2 * e] | ((u32)hb[q * 8 + 2 * e + 1] << 16);
        *reinterpret_cast<uint4*>(T + base + q * 8) = make_uint4(w[0], w[1], w[2], w[3]);
    }
}

// ---------------- MFMA GEMM (m97 structure): Y = (A @ Bt^T + bias)*scl ----------------
template<int NFN, bool OUTBF>
__global__ __launch_bounds__(256, 3)
void mfma_gemm(const u16* __restrict__ A,
               const u16* __restrict__ B0, const u16* __restrict__ B1,
               const u16* __restrict__ B2,
               const float* __restrict__ bias0, const float* __restrict__ bias1,
               const float* __restrict__ bias2,
               float s0, float s1, float s2,
               void* __restrict__ Y0, void* __restrict__ Y1, void* __restrict__ Y2,
               int M, int N, int K)
{
    constexpr int TNB = NFN * 32;

    const int z = blockIdx.z;
    const u16*   Bt   = (z == 0) ? B0 : (z == 1) ? B1 : B2;
    const float* bias = (z == 0) ? bias0 : (z == 1) ? bias1 : bias2;
    const float  scl  = (z == 0) ? s0 : (z == 1) ? s1 : s2;
    void*        Y    = (z == 0) ? Y0 : (z == 1) ? Y1 : Y2;

    __shared__ u16 lds[(128 + TNB) * 32];
    u16* lA = lds;               // [128][32]
    u16* lB = lds + 128 * 32;    // [TNB][32]

    const int tid  = threadIdx.x;
    const int wid  = tid >> 6, lane = tid & 63;
    const int wr   = wid >> 1, wc = wid & 1;
    const int lr   = lane & 15, lg = lane >> 4;
    const int bm   = blockIdx.y * 128, bn = blockIdx.x * TNB;

    const int srow = lane >> 2;          // 0..15 within a 16-row chunk
    const int scol = (lane & 3) * 8;     // bf16 col within 32

    f32x4 acc[4][NFN];
#pragma unroll
    for (int i = 0; i < 4; ++i)
#pragma unroll
        for (int j = 0; j < NFN; ++j) acc[i][j] = (f32x4)0.0f;

    for (int k0 = 0; k0 < K; k0 += 32) {
#pragma unroll
        for (int q = 0; q < 2; ++q) {
            int ch = wid + q * 4;
            gload16(A + (size_t)(bm + ch * 16 + srow) * K + k0 + scol,
                    lA + ch * 512);
        }
#pragma unroll
        for (int q = 0; q < TNB / 64; ++q) {
            int ch = wid + q * 4;
            gload16(Bt + (size_t)(bn + ch * 16 + srow) * K + k0 + scol,
                    lB + ch * 512);
        }
        __syncthreads();

        bf16x8 a0[4], b0[NFN];
#pragma unroll
        for (int mf = 0; mf < 4; ++mf)
            a0[mf] = *reinterpret_cast<const bf16x8*>(
                lA + (wr * 64 + mf * 16 + lr) * 32 + lg * 8);
#pragma unroll
        for (int nf = 0; nf < NFN; ++nf)
            b0[nf] = *reinterpret_cast<const bf16x8*>(
                lB + (wc * NFN * 16 + nf * 16 + lr) * 32 + lg * 8);
#pragma unroll
        for (int mf = 0; mf < 4; ++mf)
#pragma unroll
            for (int nf = 0; nf < NFN; ++nf)
                acc[mf][nf] = __builtin_amdgcn_mfma_f32_16x16x32_bf16(
                    a0[mf], b0[nf], acc[mf][nf], 0, 0, 0);
        __syncthreads();
    }

    // epilogue: C/D layout col=lane&15, row=(lane>>4)*4+reg  [m89/m91]
#pragma unroll
    for (int nf = 0; nf < NFN; ++nf) {
        int col = bn + wc * NFN * 16 + nf * 16 + lr;
        float bs = bias[col];
#pragma unroll
        for (int mf = 0; mf < 4; ++mf) {
#pragma unroll
            for (int r = 0; r < 4; ++r) {
                int row = bm + wr * 64 + mf * 16 + lg * 4 + r;
                float val = (acc[mf][nf][r] + bs) * scl;
                if (OUTBF)
                    ((u16*)Y)[(size_t)row * N + col] = f2bf(val);
                else
                    ((float*)Y)[(size_t)row * N + col] = val;
            }
        }
    }
}

// --------- sliding-window attention: swapped-QK MFMA, lane-local softmax ---------
// 4 waves x 16 q-rows (QB=64), KB=64. S^T = mfma(K,Q): lane owns query lr,
// keys nf*16+lg*4+r. Softmax lane-local + 2 shfl. Q pre-scaled by 0.125.
__global__ __launch_bounds__(256, 4)
void attn_mfma_kernel(const u16* __restrict__ Qb, const u16* __restrict__ Kb,
                      const u16* __restrict__ Vb, u16* __restrict__ AOh)
{
    __shared__ u16 Ks[64 * 64];
    __shared__ u16 Vt[64 * 64];
    __shared__ u16 Ps[4 * 16 * 64];   // per-wave private [16 q][64 key] swizzled

    constexpr float L2E = 1.44269504f;

    // XCD-chunked bijective swizzle
    const int nwg = gridDim.x * gridDim.y * gridDim.z;       // 1024 for B=2
    int n  = blockIdx.x + gridDim.x * (blockIdx.y + gridDim.y * blockIdx.z);
    int sw = (n & 7) * (nwg >> 3) + (n >> 3);
    const int qb = sw & 31;
    const int h  = (sw >> 5) & 15;
    const int b  = sw >> 9;

    const int i0  = qb * 64;
    const int tid = threadIdx.x;
    const int wid = tid >> 6, lane = tid & 63;
    const int lr  = lane & 15, lg = lane >> 4;
    const int l7  = lr & 7;

    const u16* Kh = Kb + (size_t)b * S_LEN * EMB + (size_t)h * S_LEN * HDIM;

    // Q fragments (pre-scaled by 0.125 in the QKV GEMM epilogue)
    bf16x8 qa[2];
    {
        const u16* qp = Qb + ((size_t)(b * S_LEN + i0 + wid * 16 + lr)) * EMB
                        + h * HDIM + lg * 8;
        qa[0] = *reinterpret_cast<const bf16x8*>(qp);
        qa[1] = *reinterpret_cast<const bf16x8*>(qp + 32);
    }

    float m2 = -1e30f, l = 0.0f;      // per-lane: query lr (base-2 units)
    f32x4 o[4];
#pragma unroll
    for (int nf = 0; nf < 4; ++nf) o[nf] = (f32x4)0.0f;

    const int tlo = (qb < 4) ? 0 : qb - 4;
    const int thi = (qb > 27) ? 31 : qb + 4;
    const int qg  = i0 + wid * 16 + lr;          // this lane's query row

    for (int t = tlo; t <= thi; ++t) {
        __syncthreads();   // all waves done reading Ks/Vt of prev tile

        // ---- stage K: coalesced chunks; swizzled b128 LDS writes ----
#pragma unroll
        for (int q = 0; q < 2; ++q) {
            int cc = tid + q * 256;           // 0..511
            int j = cc >> 3, g = cc & 7;
            uint4 v = *reinterpret_cast<const uint4*>(
                Kh + (size_t)(t * 64 + j) * HDIM + g * 8);
            *reinterpret_cast<uint4*>(Ks + j * 64 + ((g ^ (j & 7)) << 3)) = v;
        }
        // ---- stage V transposed: Vt[d][j], paired-row b32 writes ----
        {
            int jp = (tid & 31) * 2, dc = tid >> 5;
            const u16* vp = Vb + ((size_t)(b * S_LEN + t * 64 + jp)) * EMB
                            + h * HDIM + dc * 8;
            uint4 r0 = *reinterpret_cast<const uint4*>(vp);
            uint4 r1 = *reinterpret_cast<const uint4*>(vp + EMB);
            const u16* e0 = reinterpret_cast<const u16*>(&r0);
            const u16* e1 = reinterpret_cast<const u16*>(&r1);
            int jg = jp >> 3, jl = jp & 7;
#pragma unroll
            for (int e = 0; e < 8; ++e) {
                int d = dc * 8 + e;
                u32 w = (u32)e0[e] | ((u32)e1[e] << 16);
                *reinterpret_cast<u32*>(Vt + d * 64 + ((jg ^ (d & 7)) << 3) + jl) = w;
            }
        }
        __syncthreads();

        // ---- QK^T swapped: S^T tiles, lane holds S[key=nf*16+lg*4+r][q=lr] ----
        f32x4 s[4];
#pragma unroll
        for (int nf = 0; nf < 4; ++nf) s[nf] = (f32x4)0.0f;
#pragma unroll
        for (int ks = 0; ks < 2; ++ks) {
            int cg = (ks * 4 + lg) ^ l7;
#pragma unroll
            for (int nf = 0; nf < 4; ++nf) {
                bf16x8 kf = *reinterpret_cast<const bf16x8*>(
                    Ks + (nf * 16 + lr) * 64 + (cg << 3));
                s[nf] = __builtin_amdgcn_mfma_f32_16x16x32_bf16(kf, qa[ks], s[nf], 0, 0, 0);
            }
        }

        // ---- window mask: only edge tiles need it (W=256 = 4 full tiles) ----
        if (t == qb - 4 || t == qb + 4) {
            int klo = qg - WIN, khi = qg + WIN;
#pragma unroll
            for (int nf = 0; nf < 4; ++nf) {
#pragma unroll
                for (int r = 0; r < 4; ++r) {
                    int kg = t * 64 + nf * 16 + lg * 4 + r;
                    bool ok = (kg >= klo) && (kg < khi);
                    s[nf][r] = ok ? s[nf][r] : -1e30f;
                }
            }
        }

        // ---- lane-local max over 16 + allreduce across 4 lanes sharing lr ----
        float tmax = s[0][0];
#pragma unroll
        for (int nf = 0; nf < 4; ++nf)
#pragma unroll
            for (int r = 0; r < 4; ++r) tmax = fmaxf(tmax, s[nf][r]);
        tmax = fmaxf(tmax, __shfl_xor(tmax, 16));
        tmax = fmaxf(tmax, __shfl_xor(tmax, 32));
        float tmax2 = tmax * L2E;

        // T13 defer-rescale
        bool need = tmax2 > m2 + 12.0f;
        if (__any(need)) {
            float mn2 = fmaxf(m2, tmax2);
            float sc = __builtin_amdgcn_exp2f(m2 - mn2);
            m2 = mn2;
            l *= sc;
#pragma unroll
            for (int r = 0; r < 4; ++r) {
                float scr = __shfl(sc, lg * 4 + r);   // factor for o-row lg*4+r
#pragma unroll
                for (int nf = 0; nf < 4; ++nf) o[nf][r] *= scr;
            }
        }

        // ---- exp2 + row sum + packed P write (per-wave private tile) ----
        float ps = 0.0f;
#pragma unroll
        for (int nf = 0; nf < 4; ++nf) {
            float p0 = __builtin_amdgcn_exp2f(fmaf(s[nf][0], L2E, -m2));
            float p1 = __builtin_amdgcn_exp2f(fmaf(s[nf][1], L2E, -m2));
            float p2 = __builtin_amdgcn_exp2f(fmaf(s[nf][2], L2E, -m2));
            float p3 = __builtin_amdgcn_exp2f(fmaf(s[nf][3], L2E, -m2));
            ps += (p0 + p1) + (p2 + p3);
            u32 pk0 = cvt_pk_bf16(p0, p1);
            u32 pk1 = cvt_pk_bf16(p2, p3);
            int idx16 = wid * 1024 + lr * 64 +
                        (((nf * 2 + (lg >> 1)) ^ l7) << 3) + (lg & 1) * 4;
            *reinterpret_cast<uint2*>(Ps + idx16) = make_uint2(pk0, pk1);
        }
        ps += __shfl_xor(ps, 16);
        ps += __shfl_xor(ps, 32);
        l += ps;

        // ---- PV: O[16q x 64d] += P[16q x 64k] * V[64k x 16d]x4 ----
#pragma unroll
        for (int ks = 0; ks < 2; ++ks) {
            int cg = (ks * 4 + lg) ^ l7;
            bf16x8 pf = *reinterpret_cast<const bf16x8*>(
                Ps + wid * 1024 + lr * 64 + (cg << 3));
#pragma unroll
            for (int nf = 0; nf < 4; ++nf) {
                bf16x8 vf = *reinterpret_cast<const bf16x8*>(
                    Vt + (nf * 16 + lr) * 64 + (cg << 3));
                o[nf] = __builtin_amdgcn_mfma_f32_16x16x32_bf16(pf, vf, o[nf], 0, 0, 0);
            }
        }
    }

    // ---- epilogue: per-row normalize (factor from lane lr'=lg*4+r), store ----
    float inv = 1.0f / l;
#pragma unroll
    for (int r = 0; r < 4; ++r) {
        float invr = __shfl(inv, lg * 4 + r);
#pragma unroll
        for (int nf = 0; nf < 4; ++nf) {
            size_t idx = ((size_t)(b * S_LEN + i0 + wid * 16 + lg * 4 + r)) * EMB
                         + h * HDIM + nf * 16 + lr;
            AOh[idx] = f2bf(o[nf][r] * invr);
        }
    }
}

extern "C" void kernel_launch(void* const* d_in, const int* in_sizes, int n_in,
                              void* d_out, int out_size, void* d_ws, size_t ws_size,
                              hipStream_t stream)
{
    (void)n_in; (void)out_size; (void)ws_size;
    const float* x  = (const float*)d_in[0];
    const float* Wq = (const float*)d_in[1];
    const float* bq = (const float*)d_in[2];
    const float* Wk = (const float*)d_in[3];
    const float* bk = (const float*)d_in[4];
    const float* Wv = (const float*)d_in[5];
    const float* bv = (const float*)d_in[6];
    const float* Wo = (const float*)d_in[7];
    const float* bo = (const float*)d_in[8];
    float* out = (float*)d_out;

    const int B = in_sizes[0] / (S_LEN * EMB);
    const int M = B * S_LEN;

    u16* xh  = (u16*)d_ws;
    u16* WtQ = xh  + (size_t)M * EMB;
    u16* WtK = WtQ + (size_t)EMB * EMB;
    u16* WtV = WtK + (size_t)EMB * EMB;
    u16* WtO = WtV + (size_t)EMB * EMB;
    u16* Qb  = WtO + (size_t)EMB * EMB;
    u16* Kb  = Qb + (size_t)M * EMB;
    u16* Vb  = Kb + (size_t)M * EMB;
    u16* AOh = Vb + (size_t)M * EMB;

    int n4 = M * EMB / 4;
    convert_bf16_kernel<<<n4 / 256, 256, 0, stream>>>(x, xh, n4);

    dim3 gt(EMB / 64, EMB / 64, 4);
    transpose_w_kernel<<<gt, 256, 0, stream>>>(Wq, Wk, Wv, Wo, WtQ, WtK, WtV, WtO);

    // QKV projections; Q scaled by exact 0.125 (softmax scale folded out)
    dim3 g1(EMB / 128, M / 128, 3);
    mfma_gemm<4, true><<<g1, 256, 0, stream>>>(
        xh, WtQ, WtK, WtV, bq, bk, bv, 0.125f, 1.0f, 1.0f,
        Qb, Kb, Vb, M, EMB, EMB);

    // sliding-window attention -> AO bf16
    dim3 g2(S_LEN / 64, HEADS, B);
    attn_mfma_kernel<<<g2, 256, 0, stream>>>(Qb, Kb, Vb, AOh);

    // output projection -> f32 out
    dim3 g3(EMB / 64, M / 128, 1);
    mfma_gemm<2, false><<<g3, 256, 0, stream>>>(
        AOh, WtO, WtO, WtO, bo, bo, bo, 1.0f, 1.0f, 1.0f,
        out, out, out, M, EMB, EMB);
}